// Round 1
// baseline (589.186 us; speedup 1.0000x reference)
//
#include <hip/hip_runtime.h>
#include <math.h>

#define B_   4
#define L_   4096
#define H_   8
#define D_   64
#define SK   45            // sample_k
#define NT   45            // n_top
#define BH   (B_*H_)       // 32
#define SCALE 0.125f       // 1/sqrt(64)
#define NJC  16            // key chunks for attn*V partials (256 keys each)

// ---------------- Phase 1: M[b,h,q] = max_s(QK_s) - mean_s(QK_s) ----------------
// one wave per (b,h,q); 4 s-groups x 16 lanes; each group handles s = 4t+g.
__global__ __launch_bounds__(256) void k_m(const float* __restrict__ q,
                                           const float* __restrict__ k,
                                           const int* __restrict__ samp,
                                           float* __restrict__ M) {
  const int wid  = blockIdx.x * 4 + (threadIdx.x >> 6); // (b*H+h)*L + qi
  const int lane = threadIdx.x & 63;
  const int g    = lane >> 4;   // s-group
  const int r    = lane & 15;   // d-quad
  const int bh   = wid >> 12;
  const int qi   = wid & (L_ - 1);
  const int b    = bh >> 3, h = bh & 7;

  const float4* qrow = (const float4*)(q + (((size_t)b * L_ + qi) * H_ + h) * D_);
  const float4  qv   = qrow[r];
  const int* srow = samp + (size_t)qi * SK;

  float gmax = -1e30f, gsum = 0.f;
  #pragma unroll
  for (int i = 0; i < 12; ++i) {
    const int s = i * 4 + g;
    const bool valid = (s < SK);
    const int idx = srow[valid ? s : 0];
    const float4* krow = (const float4*)(k + (((size_t)b * L_ + idx) * H_ + h) * D_);
    const float4 kv = krow[r];
    float p = qv.x * kv.x + qv.y * kv.y + qv.z * kv.z + qv.w * kv.w;
    p += __shfl_xor(p, 1);
    p += __shfl_xor(p, 2);
    p += __shfl_xor(p, 4);
    p += __shfl_xor(p, 8);
    if (valid) { gmax = fmaxf(gmax, p); gsum += p; }
  }
  gmax = fmaxf(gmax, __shfl_xor(gmax, 16));
  gmax = fmaxf(gmax, __shfl_xor(gmax, 32));
  gsum += __shfl_xor(gsum, 16);
  gsum += __shfl_xor(gsum, 32);
  if (lane == 0) M[wid] = gmax - gsum * (1.0f / SK);
}

// ---------------- Phase 2: top-45 indices of M per (b,h) ----------------
__global__ __launch_bounds__(256) void k_topk(const float* __restrict__ M,
                                              int* __restrict__ top) {
  __shared__ float vals[L_];
  __shared__ float red_v[4];
  __shared__ int   red_i[4];
  const int bh = blockIdx.x;
  const float* Mrow = M + (size_t)bh * L_;
  for (int i = threadIdx.x; i < L_; i += 256) vals[i] = Mrow[i];
  __syncthreads();
  for (int t = 0; t < NT; ++t) {
    float bv = -1e30f; int bi = 0;
    for (int i = threadIdx.x; i < L_; i += 256) {
      const float v = vals[i];
      if (v > bv) { bv = v; bi = i; }  // first (lowest i) kept within thread
    }
    #pragma unroll
    for (int off = 1; off < 64; off <<= 1) {
      const float ov = __shfl_xor(bv, off);
      const int   oi = __shfl_xor(bi, off);
      if (ov > bv || (ov == bv && oi < bi)) { bv = ov; bi = oi; }
    }
    const int w = threadIdx.x >> 6;
    if ((threadIdx.x & 63) == 0) { red_v[w] = bv; red_i[w] = bi; }
    __syncthreads();
    if (threadIdx.x == 0) {
      #pragma unroll
      for (int j = 1; j < 4; ++j)
        if (red_v[j] > bv || (red_v[j] == bv && red_i[j] < bi)) { bv = red_v[j]; bi = red_i[j]; }
      top[bh * NT + t] = bi;
      vals[bi] = -1e30f;
    }
    __syncthreads();
  }
}

// ---------------- V mean over L per (b,h,d) ----------------
__global__ __launch_bounds__(256) void k_vmean(const float* __restrict__ v,
                                               float* __restrict__ vmean) {
  const int bh = blockIdx.x, b = bh >> 3, h = bh & 7;
  const int d = threadIdx.x & 63, w = threadIdx.x >> 6;
  float acc = 0.f;
  for (int l = w; l < L_; l += 4)
    acc += v[(((size_t)b * L_ + l) * H_ + h) * D_ + d];
  __shared__ float part[4][64];
  part[w][d] = acc;
  __syncthreads();
  if (w == 0)
    vmean[bh * D_ + d] = (part[0][d] + part[1][d] + part[2][d] + part[3][d]) * (1.0f / L_);
}

// ---------------- scores = (Q_top @ K^T) * scale  (written into d_out scratch) ----------------
__global__ __launch_bounds__(256) void k_scores(const float* __restrict__ q,
                                                const float* __restrict__ k,
                                                const int* __restrict__ top,
                                                float* __restrict__ scores) {
  __shared__ float k_lds[256 * 65];                 // stride 65: conflict-free scalar reads
  __shared__ __align__(16) float q_lds[NT * D_];    // broadcast reads (b128, same addr)
  const int bh = blockIdx.x >> 4, kb = blockIdx.x & 15;
  const int b = bh >> 3, h = bh & 7;

  // stage K chunk (256 rows x 64)
  const float* kbase = k + (((size_t)b * L_ + kb * 256) * H_ + h) * D_;
  for (int fi = threadIdx.x; fi < 4096; fi += 256) {
    const int j = fi >> 4, d4 = fi & 15;
    const float4 kv = *(const float4*)(kbase + (size_t)j * H_ * D_ + d4 * 4);
    float* dst = &k_lds[j * 65 + d4 * 4];
    dst[0] = kv.x; dst[1] = kv.y; dst[2] = kv.z; dst[3] = kv.w;
  }
  // stage gathered Q_top rows
  for (int fi = threadIdx.x; fi < NT * D_; fi += 256) {
    const int n = fi >> 6, d = fi & 63;
    const int qi = top[bh * NT + n];
    q_lds[fi] = q[(((size_t)b * L_ + qi) * H_ + h) * D_ + d];
  }
  __syncthreads();

  const int w = threadIdx.x >> 6, lane = threadIdx.x & 63;
  const int jl = w * 64 + lane;          // local key 0..255
  const int jj = kb * 256 + jl;          // global key
  const float* krow = &k_lds[jl * 65];
  for (int n = 0; n < NT; ++n) {
    float acc = 0.f;
    #pragma unroll
    for (int d4 = 0; d4 < 16; ++d4) {
      const float4 qq = *(const float4*)&q_lds[n * 64 + d4 * 4];
      acc += qq.x * krow[d4 * 4 + 0] + qq.y * krow[d4 * 4 + 1]
           + qq.z * krow[d4 * 4 + 2] + qq.w * krow[d4 * 4 + 3];
    }
    scores[((size_t)bh * NT + n) * L_ + jj] = acc * SCALE;
  }
}

// ---------------- row softmax over 4096, in place ----------------
__global__ __launch_bounds__(256) void k_softmax(float* __restrict__ scores) {
  __shared__ float buf[L_];
  __shared__ float red[4];
  const size_t base = (size_t)blockIdx.x * L_;
  float lm = -1e30f;
  for (int i = threadIdx.x; i < L_; i += 256) {
    const float v = scores[base + i];
    buf[i] = v;
    lm = fmaxf(lm, v);
  }
  #pragma unroll
  for (int o = 1; o < 64; o <<= 1) lm = fmaxf(lm, __shfl_xor(lm, o));
  if ((threadIdx.x & 63) == 0) red[threadIdx.x >> 6] = lm;
  __syncthreads();
  const float m = fmaxf(fmaxf(red[0], red[1]), fmaxf(red[2], red[3]));
  float ls = 0.f;
  for (int i = threadIdx.x; i < L_; i += 256) {
    const float p = __expf(buf[i] - m);
    buf[i] = p;
    ls += p;
  }
  #pragma unroll
  for (int o = 1; o < 64; o <<= 1) ls += __shfl_xor(ls, o);
  __syncthreads();
  if ((threadIdx.x & 63) == 0) red[threadIdx.x >> 6] = ls;
  __syncthreads();
  const float inv = 1.0f / (red[0] + red[1] + red[2] + red[3]);
  for (int i = threadIdx.x; i < L_; i += 256) scores[base + i] = buf[i] * inv;
}

// ---------------- attn @ V, key-chunk partials ----------------
__global__ __launch_bounds__(256) void k_av(const float* __restrict__ p,
                                            const float* __restrict__ v,
                                            float* __restrict__ opart) {
  const int bh = blockIdx.x >> 4, jc = blockIdx.x & 15;
  const int b = bh >> 3, h = bh & 7;
  const int w = threadIdx.x >> 6, d = threadIdx.x & 63;
  float o[12];
  #pragma unroll
  for (int t = 0; t < 12; ++t) o[t] = 0.f;
  const int nmax = (w == 0) ? 12 : 11;   // n = w + 4t, n < 45
  const float* vbase = v + (((size_t)b * L_ + jc * 256) * H_ + h) * D_ + d;
  const float* pbase = p + (size_t)bh * NT * L_ + jc * 256;
  for (int j = 0; j < 256; ++j) {
    const float vv = vbase[(size_t)j * H_ * D_];
    #pragma unroll
    for (int t = 0; t < 12; ++t) {
      if (t < nmax) {
        const int n = w + 4 * t;
        o[t] += pbase[(size_t)n * L_ + j] * vv;
      }
    }
  }
  for (int t = 0; t < nmax; ++t) {
    const int n = w + 4 * t;
    opart[(((size_t)bh * NJC + jc) * NT + n) * D_ + d] = o[t];
  }
}

// ---------------- fill output with broadcast V-mean ----------------
__global__ __launch_bounds__(256) void k_fill(const float* __restrict__ vmean,
                                              float* __restrict__ out) {
  const size_t i = (size_t)blockIdx.x * 256 + threadIdx.x;  // float4 index
  const int d4 = (int)(i & 15);
  const int bh = (int)(i >> 16);                            // L_*D_/4 = 65536 per bh
  const float4* vm = (const float4*)(vmean + bh * D_);
  ((float4*)out)[i] = vm[d4];
}

// ---------------- combine partials, scatter into out rows ----------------
__global__ void k_av2(const float* __restrict__ opart,
                      const int* __restrict__ top,
                      float* __restrict__ out) {
  const int bhn = blockIdx.x, bh = bhn / NT, n = bhn % NT;
  const int d = threadIdx.x;
  float acc = 0.f;
  #pragma unroll
  for (int jc = 0; jc < NJC; ++jc)
    acc += opart[(((size_t)bh * NJC + jc) * NT + n) * D_ + d];
  const int qi = top[bh * NT + n];
  out[((size_t)bh * L_ + qi) * D_ + d] = acc;
}

extern "C" void kernel_launch(void* const* d_in, const int* in_sizes, int n_in,
                              void* d_out, int out_size, void* d_ws, size_t ws_size,
                              hipStream_t stream) {
  const float* q    = (const float*)d_in[0];
  const float* k    = (const float*)d_in[1];
  const float* v    = (const float*)d_in[2];
  const int*   samp = (const int*)d_in[3];
  float* out = (float*)d_out;
  char*  ws  = (char*)d_ws;

  float* M     = (float*)ws;                 // 131072 f = 512 KB
  int*   top   = (int*)(ws + 524288);        // 1440 ints
  float* vmean = (float*)(ws + 532480);      // 2048 f
  float* opart = (float*)(ws + 540672);      // 32*16*45*64 f = 5.9 MB
  float* scores = out;                       // d_out doubles as 23.6 MB scratch

  hipLaunchKernelGGL(k_m,       dim3(BH * L_ / 4), dim3(256), 0, stream, q, k, samp, M);
  hipLaunchKernelGGL(k_topk,    dim3(BH),          dim3(256), 0, stream, M, top);
  hipLaunchKernelGGL(k_vmean,   dim3(BH),          dim3(256), 0, stream, v, vmean);
  hipLaunchKernelGGL(k_scores,  dim3(BH * 16),     dim3(256), 0, stream, q, k, top, scores);
  hipLaunchKernelGGL(k_softmax, dim3(BH * NT),     dim3(256), 0, stream, scores);
  hipLaunchKernelGGL(k_av,      dim3(BH * NJC),    dim3(256), 0, stream, scores, v, opart);
  hipLaunchKernelGGL(k_fill,    dim3(8192),        dim3(256), 0, stream, vmean, out);
  hipLaunchKernelGGL(k_av2,     dim3(BH * NT),     dim3(64),  0, stream, opart, top, out);
}

// Round 4
// 357.222 us; speedup vs baseline: 1.6494x; 1.6494x over previous
//
#include <hip/hip_runtime.h>
#include <math.h>

#define B_   4
#define L_   4096
#define H_   8
#define D_   64
#define SK   45            // sample_k
#define NT   45            // n_top
#define BH   (B_*H_)       // 32
#define SCALE 0.125f       // 1/sqrt(64)
#define NJC  16            // key chunks for attn*V partials (256 keys each)
#define VCH  64            // L-rows per vmean chunk

// ---------------- Phase 1: M[b,h,q] = max_s(QK_s) - mean_s(QK_s) ----------------
// one wave per (b,h,q); 4 s-groups x 16 lanes; each group handles s = 4t+g.
__global__ __launch_bounds__(256) void k_m(const float* __restrict__ q,
                                           const float* __restrict__ k,
                                           const int* __restrict__ samp,
                                           float* __restrict__ M) {
  const int wid  = blockIdx.x * 4 + (threadIdx.x >> 6); // (b*H+h)*L + qi
  const int lane = threadIdx.x & 63;
  const int g    = lane >> 4;   // s-group
  const int r    = lane & 15;   // d-quad
  const int bh   = wid >> 12;
  const int qi   = wid & (L_ - 1);
  const int b    = bh >> 3, h = bh & 7;

  const float4* qrow = (const float4*)(q + (((size_t)b * L_ + qi) * H_ + h) * D_);
  const float4  qv   = qrow[r];
  const int* srow = samp + (size_t)qi * SK;

  float gmax = -1e30f, gsum = 0.f;
  #pragma unroll
  for (int i = 0; i < 12; ++i) {
    const int s = i * 4 + g;
    const bool valid = (s < SK);
    const int idx = srow[valid ? s : 0];
    const float4* krow = (const float4*)(k + (((size_t)b * L_ + idx) * H_ + h) * D_);
    const float4 kv = krow[r];
    float p = qv.x * kv.x + qv.y * kv.y + qv.z * kv.z + qv.w * kv.w;
    p += __shfl_xor(p, 1);
    p += __shfl_xor(p, 2);
    p += __shfl_xor(p, 4);
    p += __shfl_xor(p, 8);
    if (valid) { gmax = fmaxf(gmax, p); gsum += p; }
  }
  gmax = fmaxf(gmax, __shfl_xor(gmax, 16));
  gmax = fmaxf(gmax, __shfl_xor(gmax, 32));
  gsum += __shfl_xor(gsum, 16);
  gsum += __shfl_xor(gsum, 32);
  if (lane == 0) M[wid] = gmax - gsum * (1.0f / SK);
}

// ---------------- Phase 2: top-45 indices of M per (b,h) ----------------
__global__ __launch_bounds__(256) void k_topk(const float* __restrict__ M,
                                              int* __restrict__ top) {
  __shared__ float vals[L_];
  __shared__ float red_v[4];
  __shared__ int   red_i[4];
  const int bh = blockIdx.x;
  const float* Mrow = M + (size_t)bh * L_;
  for (int i = threadIdx.x; i < L_; i += 256) vals[i] = Mrow[i];
  __syncthreads();
  for (int t = 0; t < NT; ++t) {
    float bv = -1e30f; int bi = 0;
    for (int i = threadIdx.x; i < L_; i += 256) {
      const float v = vals[i];
      if (v > bv) { bv = v; bi = i; }  // first (lowest i) kept within thread
    }
    #pragma unroll
    for (int off = 1; off < 64; off <<= 1) {
      const float ov = __shfl_xor(bv, off);
      const int   oi = __shfl_xor(bi, off);
      if (ov > bv || (ov == bv && oi < bi)) { bv = ov; bi = oi; }
    }
    const int w = threadIdx.x >> 6;
    if ((threadIdx.x & 63) == 0) { red_v[w] = bv; red_i[w] = bi; }
    __syncthreads();
    if (threadIdx.x == 0) {
      #pragma unroll
      for (int j = 1; j < 4; ++j)
        if (red_v[j] > bv || (red_v[j] == bv && red_i[j] < bi)) { bv = red_v[j]; bi = red_i[j]; }
      top[bh * NT + t] = bi;
      vals[bi] = -1e30f;
    }
    __syncthreads();
  }
}

// ---------------- V mean, stage 1: per-(b, L-chunk) partial sums over all (h,d) ----------------
// grid = B_ * (L_/VCH) = 256 blocks; block reads a contiguous VCH x 512-float panel.
__global__ __launch_bounds__(256) void k_vmean1(const float* __restrict__ v,
                                                float* __restrict__ vpart) {
  const int blk = blockIdx.x;
  const int b   = blk >> 6;          // 64 chunks per b
  const int c   = blk & 63;
  const int t   = threadIdx.x;
  const int hd4 = t & 127;           // float4 index within the 512-float (h,d) row
  const int p   = t >> 7;            // 0/1: row parity
  const float4* base = (const float4*)(v + ((size_t)b * L_ + (size_t)c * VCH) * (H_ * D_)) + hd4;
  float4 acc = {0.f, 0.f, 0.f, 0.f};
  for (int l = p; l < VCH; l += 2) {
    const float4 x = base[(size_t)l * 128];
    acc.x += x.x; acc.y += x.y; acc.z += x.z; acc.w += x.w;
  }
  __shared__ float4 s[2][128];
  s[p][hd4] = acc;
  __syncthreads();
  if (t < 128) {
    const float4 a = s[0][t], b2 = s[1][t];
    const float4 r = {a.x + b2.x, a.y + b2.y, a.z + b2.z, a.w + b2.w};
    ((float4*)vpart)[(size_t)blk * 128 + t] = r;
  }
}

// ---------------- V mean, stage 2: reduce 64 chunks ----------------
__global__ __launch_bounds__(512) void k_vmean2(const float* __restrict__ vpart,
                                                float* __restrict__ vmean) {
  const int b = blockIdx.x, t = threadIdx.x;   // t = hd index 0..511
  float acc = 0.f;
  for (int c = 0; c < 64; ++c)
    acc += vpart[((size_t)(b * 64 + c)) * 512 + t];
  vmean[b * 512 + t] = acc * (1.0f / L_);
}

// ---------------- scores = (Q_top @ K^T) * scale  (written into d_out scratch) ----------------
__global__ __launch_bounds__(256) void k_scores(const float* __restrict__ q,
                                                const float* __restrict__ k,
                                                const int* __restrict__ top,
                                                float* __restrict__ scores) {
  __shared__ float k_lds[256 * 65];                 // stride 65: conflict-free scalar reads
  __shared__ __align__(16) float q_lds[NT * D_];    // broadcast reads (b128, same addr)
  const int bh = blockIdx.x >> 4, kb = blockIdx.x & 15;
  const int b = bh >> 3, h = bh & 7;

  // stage K chunk (256 rows x 64)
  const float* kbase = k + (((size_t)b * L_ + kb * 256) * H_ + h) * D_;
  for (int fi = threadIdx.x; fi < 4096; fi += 256) {
    const int j = fi >> 4, d4 = fi & 15;
    const float4 kv = *(const float4*)(kbase + (size_t)j * H_ * D_ + d4 * 4);
    float* dst = &k_lds[j * 65 + d4 * 4];
    dst[0] = kv.x; dst[1] = kv.y; dst[2] = kv.z; dst[3] = kv.w;
  }
  // stage gathered Q_top rows
  for (int fi = threadIdx.x; fi < NT * D_; fi += 256) {
    const int n = fi >> 6, d = fi & 63;
    const int qi = top[bh * NT + n];
    q_lds[fi] = q[(((size_t)b * L_ + qi) * H_ + h) * D_ + d];
  }
  __syncthreads();

  const int w = threadIdx.x >> 6, lane = threadIdx.x & 63;
  const int jl = w * 64 + lane;          // local key 0..255
  const int jj = kb * 256 + jl;          // global key
  const float* krow = &k_lds[jl * 65];
  for (int n = 0; n < NT; ++n) {
    float acc = 0.f;
    #pragma unroll
    for (int d4 = 0; d4 < 16; ++d4) {
      const float4 qq = *(const float4*)&q_lds[n * 64 + d4 * 4];
      acc += qq.x * krow[d4 * 4 + 0] + qq.y * krow[d4 * 4 + 1]
           + qq.z * krow[d4 * 4 + 2] + qq.w * krow[d4 * 4 + 3];
    }
    scores[((size_t)bh * NT + n) * L_ + jj] = acc * SCALE;
  }
}

// ---------------- row softmax over 4096, in place ----------------
__global__ __launch_bounds__(256) void k_softmax(float* __restrict__ scores) {
  __shared__ float buf[L_];
  __shared__ float red[4];
  const size_t base = (size_t)blockIdx.x * L_;
  float lm = -1e30f;
  for (int i = threadIdx.x; i < L_; i += 256) {
    const float v = scores[base + i];
    buf[i] = v;
    lm = fmaxf(lm, v);
  }
  #pragma unroll
  for (int o = 1; o < 64; o <<= 1) lm = fmaxf(lm, __shfl_xor(lm, o));
  if ((threadIdx.x & 63) == 0) red[threadIdx.x >> 6] = lm;
  __syncthreads();
  const float m = fmaxf(fmaxf(red[0], red[1]), fmaxf(red[2], red[3]));
  float ls = 0.f;
  for (int i = threadIdx.x; i < L_; i += 256) {
    const float p = __expf(buf[i] - m);
    buf[i] = p;
    ls += p;
  }
  #pragma unroll
  for (int o = 1; o < 64; o <<= 1) ls += __shfl_xor(ls, o);
  __syncthreads();
  if ((threadIdx.x & 63) == 0) red[threadIdx.x >> 6] = ls;
  __syncthreads();
  const float inv = 1.0f / (red[0] + red[1] + red[2] + red[3]);
  for (int i = threadIdx.x; i < L_; i += 256) scores[base + i] = buf[i] * inv;
}

// ---------------- attn @ V, key-chunk partials ----------------
__global__ __launch_bounds__(256) void k_av(const float* __restrict__ p,
                                            const float* __restrict__ v,
                                            float* __restrict__ opart) {
  const int bh = blockIdx.x >> 4, jc = blockIdx.x & 15;
  const int b = bh >> 3, h = bh & 7;
  const int w = threadIdx.x >> 6, d = threadIdx.x & 63;
  float o[12];
  #pragma unroll
  for (int t = 0; t < 12; ++t) o[t] = 0.f;
  const int nmax = (w == 0) ? 12 : 11;   // n = w + 4t, n < 45
  const float* vbase = v + (((size_t)b * L_ + jc * 256) * H_ + h) * D_ + d;
  const float* pbase = p + (size_t)bh * NT * L_ + jc * 256;
  for (int j = 0; j < 256; ++j) {
    const float vv = vbase[(size_t)j * H_ * D_];
    #pragma unroll
    for (int t = 0; t < 12; ++t) {
      if (t < nmax) {
        const int n = w + 4 * t;
        o[t] += pbase[(size_t)n * L_ + j] * vv;
      }
    }
  }
  for (int t = 0; t < nmax; ++t) {
    const int n = w + 4 * t;
    opart[(((size_t)bh * NJC + jc) * NT + n) * D_ + d] = o[t];
  }
}

// ---------------- fill output with broadcast V-mean ----------------
__global__ __launch_bounds__(256) void k_fill(const float* __restrict__ vmean,
                                              float* __restrict__ out) {
  const size_t i = (size_t)blockIdx.x * 256 + threadIdx.x;  // float4 index
  const int d4 = (int)(i & 15);
  const int bh = (int)(i >> 16);                            // L_*D_/4 = 65536 per bh
  const float4* vm = (const float4*)(vmean + bh * D_);
  ((float4*)out)[i] = vm[d4];
}

// ---------------- combine partials, scatter into out rows ----------------
__global__ void k_av2(const float* __restrict__ opart,
                      const int* __restrict__ top,
                      float* __restrict__ out) {
  const int bhn = blockIdx.x, bh = bhn / NT, n = bhn % NT;
  const int d = threadIdx.x;
  float acc = 0.f;
  #pragma unroll
  for (int jc = 0; jc < NJC; ++jc)
    acc += opart[(((size_t)bh * NJC + jc) * NT + n) * D_ + d];
  const int qi = top[bh * NT + n];
  out[((size_t)bh * L_ + qi) * D_ + d] = acc;
}

extern "C" void kernel_launch(void* const* d_in, const int* in_sizes, int n_in,
                              void* d_out, int out_size, void* d_ws, size_t ws_size,
                              hipStream_t stream) {
  const float* q    = (const float*)d_in[0];
  const float* k    = (const float*)d_in[1];
  const float* v    = (const float*)d_in[2];
  const int*   samp = (const int*)d_in[3];
  float* out = (float*)d_out;
  char*  ws  = (char*)d_ws;

  float* M     = (float*)ws;                 // 131072 f = 512 KB (dead after k_topk)
  int*   top   = (int*)(ws + 524288);        // 1440 ints
  float* vmean = (float*)(ws + 532480);      // 2048 f
  float* opart = (float*)(ws + 540672);      // 32*16*45*64 f = 5.9 MB
  float* vpart = M;                          // reuse M: 256*512 f = 512 KB, after k_topk
  float* scores = out;                       // d_out doubles as 23.6 MB scratch

  hipLaunchKernelGGL(k_m,       dim3(BH * L_ / 4), dim3(256), 0, stream, q, k, samp, M);
  hipLaunchKernelGGL(k_topk,    dim3(BH),          dim3(256), 0, stream, M, top);
  hipLaunchKernelGGL(k_vmean1,  dim3(B_ * 64),     dim3(256), 0, stream, v, vpart);
  hipLaunchKernelGGL(k_vmean2,  dim3(B_),          dim3(512), 0, stream, vpart, vmean);
  hipLaunchKernelGGL(k_scores,  dim3(BH * 16),     dim3(256), 0, stream, q, k, top, scores);
  hipLaunchKernelGGL(k_softmax, dim3(BH * NT),     dim3(256), 0, stream, scores);
  hipLaunchKernelGGL(k_av,      dim3(BH * NJC),    dim3(256), 0, stream, scores, v, opart);
  hipLaunchKernelGGL(k_fill,    dim3(8192),        dim3(256), 0, stream, vmean, out);
  hipLaunchKernelGGL(k_av2,     dim3(BH * NT),     dim3(64),  0, stream, opart, top, out);
}

// Round 5
// 251.176 us; speedup vs baseline: 2.3457x; 1.4222x over previous
//
#include <hip/hip_runtime.h>
#include <math.h>

#define B_   4
#define L_   4096
#define H_   8
#define D_   64
#define SK   45            // sample_k
#define NT   45            // n_top
#define BH   (B_*H_)       // 32
#define SCALE 0.125f       // 1/sqrt(64)
#define NJC  16            // key chunks for attn*V partials (256 keys each)
#define VCH  64            // L-rows per vmean chunk
#define PLD  52            // p_lds row stride (floats): 16B-aligned, odd-ish banks

// ---------------- Phase 1: M[b,h,q] = max_s(QK_s) - mean_s(QK_s) ----------------
__global__ __launch_bounds__(256) void k_m(const float* __restrict__ q,
                                           const float* __restrict__ k,
                                           const int* __restrict__ samp,
                                           float* __restrict__ M) {
  const int wid  = blockIdx.x * 4 + (threadIdx.x >> 6); // (b*H+h)*L + qi
  const int lane = threadIdx.x & 63;
  const int g    = lane >> 4;   // s-group
  const int r    = lane & 15;   // d-quad
  const int bh   = wid >> 12;
  const int qi   = wid & (L_ - 1);
  const int b    = bh >> 3, h = bh & 7;

  const float4* qrow = (const float4*)(q + (((size_t)b * L_ + qi) * H_ + h) * D_);
  const float4  qv   = qrow[r];
  const int* srow = samp + (size_t)qi * SK;

  float gmax = -1e30f, gsum = 0.f;
  #pragma unroll
  for (int i = 0; i < 12; ++i) {
    const int s = i * 4 + g;
    const bool valid = (s < SK);
    const int idx = srow[valid ? s : 0];
    const float4* krow = (const float4*)(k + (((size_t)b * L_ + idx) * H_ + h) * D_);
    const float4 kv = krow[r];
    float p = qv.x * kv.x + qv.y * kv.y + qv.z * kv.z + qv.w * kv.w;
    p += __shfl_xor(p, 1);
    p += __shfl_xor(p, 2);
    p += __shfl_xor(p, 4);
    p += __shfl_xor(p, 8);
    if (valid) { gmax = fmaxf(gmax, p); gsum += p; }
  }
  gmax = fmaxf(gmax, __shfl_xor(gmax, 16));
  gmax = fmaxf(gmax, __shfl_xor(gmax, 32));
  gsum += __shfl_xor(gsum, 16);
  gsum += __shfl_xor(gsum, 32);
  if (lane == 0) M[wid] = gmax - gsum * (1.0f / SK);
}

// ---------------- Phase 2: top-45 indices of M per (b,h) ----------------
__global__ __launch_bounds__(256) void k_topk(const float* __restrict__ M,
                                              int* __restrict__ top) {
  __shared__ float vals[L_];
  __shared__ float red_v[4];
  __shared__ int   red_i[4];
  const int bh = blockIdx.x;
  const float* Mrow = M + (size_t)bh * L_;
  for (int i = threadIdx.x; i < L_; i += 256) vals[i] = Mrow[i];
  __syncthreads();
  for (int t = 0; t < NT; ++t) {
    float bv = -1e30f; int bi = 0;
    for (int i = threadIdx.x; i < L_; i += 256) {
      const float v = vals[i];
      if (v > bv) { bv = v; bi = i; }
    }
    #pragma unroll
    for (int off = 1; off < 64; off <<= 1) {
      const float ov = __shfl_xor(bv, off);
      const int   oi = __shfl_xor(bi, off);
      if (ov > bv || (ov == bv && oi < bi)) { bv = ov; bi = oi; }
    }
    const int w = threadIdx.x >> 6;
    if ((threadIdx.x & 63) == 0) { red_v[w] = bv; red_i[w] = bi; }
    __syncthreads();
    if (threadIdx.x == 0) {
      #pragma unroll
      for (int j = 1; j < 4; ++j)
        if (red_v[j] > bv || (red_v[j] == bv && red_i[j] < bi)) { bv = red_v[j]; bi = red_i[j]; }
      top[bh * NT + t] = bi;
      vals[bi] = -1e30f;
    }
    __syncthreads();
  }
}

// ---------------- V mean, stage 1 ----------------
__global__ __launch_bounds__(256) void k_vmean1(const float* __restrict__ v,
                                                float* __restrict__ vpart) {
  const int blk = blockIdx.x;
  const int b   = blk >> 6;
  const int c   = blk & 63;
  const int t   = threadIdx.x;
  const int hd4 = t & 127;
  const int p   = t >> 7;
  const float4* base = (const float4*)(v + ((size_t)b * L_ + (size_t)c * VCH) * (H_ * D_)) + hd4;
  float4 acc = {0.f, 0.f, 0.f, 0.f};
  for (int l = p; l < VCH; l += 2) {
    const float4 x = base[(size_t)l * 128];
    acc.x += x.x; acc.y += x.y; acc.z += x.z; acc.w += x.w;
  }
  __shared__ float4 s[2][128];
  s[p][hd4] = acc;
  __syncthreads();
  if (t < 128) {
    const float4 a = s[0][t], b2 = s[1][t];
    const float4 r = {a.x + b2.x, a.y + b2.y, a.z + b2.z, a.w + b2.w};
    ((float4*)vpart)[(size_t)blk * 128 + t] = r;
  }
}

// ---------------- V mean, stage 2 ----------------
__global__ __launch_bounds__(512) void k_vmean2(const float* __restrict__ vpart,
                                                float* __restrict__ vmean) {
  const int b = blockIdx.x, t = threadIdx.x;
  float acc = 0.f;
  for (int c = 0; c < 64; ++c)
    acc += vpart[((size_t)(b * 64 + c)) * 512 + t];
  vmean[b * 512 + t] = acc * (1.0f / L_);
}

// ---------------- scores = (Q_top @ K^T) * scale ----------------
__global__ __launch_bounds__(256) void k_scores(const float* __restrict__ q,
                                                const float* __restrict__ k,
                                                const int* __restrict__ top,
                                                float* __restrict__ scores) {
  __shared__ float k_lds[256 * 65];
  __shared__ __align__(16) float q_lds[NT * D_];
  const int bh = blockIdx.x >> 4, kb = blockIdx.x & 15;
  const int b = bh >> 3, h = bh & 7;

  const float* kbase = k + (((size_t)b * L_ + kb * 256) * H_ + h) * D_;
  for (int fi = threadIdx.x; fi < 4096; fi += 256) {
    const int j = fi >> 4, d4 = fi & 15;
    const float4 kv = *(const float4*)(kbase + (size_t)j * H_ * D_ + d4 * 4);
    float* dst = &k_lds[j * 65 + d4 * 4];
    dst[0] = kv.x; dst[1] = kv.y; dst[2] = kv.z; dst[3] = kv.w;
  }
  for (int fi = threadIdx.x; fi < NT * D_; fi += 256) {
    const int n = fi >> 6, d = fi & 63;
    const int qi = top[bh * NT + n];
    q_lds[fi] = q[(((size_t)b * L_ + qi) * H_ + h) * D_ + d];
  }
  __syncthreads();

  const int w = threadIdx.x >> 6, lane = threadIdx.x & 63;
  const int jl = w * 64 + lane;
  const int jj = kb * 256 + jl;
  const float* krow = &k_lds[jl * 65];
  for (int n = 0; n < NT; ++n) {
    float acc = 0.f;
    #pragma unroll
    for (int d4 = 0; d4 < 16; ++d4) {
      const float4 qq = *(const float4*)&q_lds[n * 64 + d4 * 4];
      acc += qq.x * krow[d4 * 4 + 0] + qq.y * krow[d4 * 4 + 1]
           + qq.z * krow[d4 * 4 + 2] + qq.w * krow[d4 * 4 + 3];
    }
    scores[((size_t)bh * NT + n) * L_ + jj] = acc * SCALE;
  }
}

// ---------------- row softmax over 4096, in place ----------------
__global__ __launch_bounds__(256) void k_softmax(float* __restrict__ scores) {
  __shared__ float buf[L_];
  __shared__ float red[4];
  const size_t base = (size_t)blockIdx.x * L_;
  float lm = -1e30f;
  for (int i = threadIdx.x; i < L_; i += 256) {
    const float v = scores[base + i];
    buf[i] = v;
    lm = fmaxf(lm, v);
  }
  #pragma unroll
  for (int o = 1; o < 64; o <<= 1) lm = fmaxf(lm, __shfl_xor(lm, o));
  if ((threadIdx.x & 63) == 0) red[threadIdx.x >> 6] = lm;
  __syncthreads();
  const float m = fmaxf(fmaxf(red[0], red[1]), fmaxf(red[2], red[3]));
  float ls = 0.f;
  for (int i = threadIdx.x; i < L_; i += 256) {
    const float p = __expf(buf[i] - m);
    buf[i] = p;
    ls += p;
  }
  #pragma unroll
  for (int o = 1; o < 64; o <<= 1) ls += __shfl_xor(ls, o);
  __syncthreads();
  if ((threadIdx.x & 63) == 0) red[threadIdx.x >> 6] = ls;
  __syncthreads();
  const float inv = 1.0f / (red[0] + red[1] + red[2] + red[3]);
  for (int i = threadIdx.x; i < L_; i += 256) scores[base + i] = buf[i] * inv;
}

// ---------------- attn @ V, key-chunk partials (LDS-staged p, v2) ----------------
// block = (bh, jc): stage p[45][256] transposed into LDS [j][PLD]; wave w owns
// j in [w*64, w*64+64), lane = d; 45 register accumulators; cross-wave reduce in LDS.
__global__ __launch_bounds__(256) void k_av(const float* __restrict__ p,
                                            const float* __restrict__ v,
                                            float* __restrict__ opart) {
  __shared__ __align__(16) float pl[256 * PLD];   // 53 KB
  const int bh = blockIdx.x >> 4, jc = blockIdx.x & 15;
  const int b = bh >> 3, h = bh & 7;
  const int tid = threadIdx.x;

  // stage p-tile transposed: global read coalesced over j, LDS write 8-way spread
  const float* pbase = p + (size_t)bh * NT * L_ + jc * 256;
  for (int fi = tid; fi < NT * 256; fi += 256) {
    const int n = fi >> 8, j = fi & 255;
    pl[j * PLD + n] = pbase[(size_t)n * L_ + j];
  }
  __syncthreads();

  const int w = tid >> 6, d = tid & 63;
  float acc[NT];
  #pragma unroll
  for (int n = 0; n < NT; ++n) acc[n] = 0.f;

  const float* vbase = v + (((size_t)b * L_ + jc * 256 + w * 64) * H_ + h) * D_ + d;
  for (int jl = 0; jl < 64; ++jl) {
    const float vv = vbase[(size_t)jl * (H_ * D_)];
    const float* pr = &pl[(w * 64 + jl) * PLD];
    #pragma unroll
    for (int n4 = 0; n4 < 11; ++n4) {
      const float4 pv = *(const float4*)(pr + n4 * 4);   // broadcast ds_read_b128
      acc[n4 * 4 + 0] += pv.x * vv;
      acc[n4 * 4 + 1] += pv.y * vv;
      acc[n4 * 4 + 2] += pv.z * vv;
      acc[n4 * 4 + 3] += pv.w * vv;
    }
    acc[44] += pr[44] * vv;
  }
  __syncthreads();

  // cross-wave reduce via reused LDS (4 * 45 * 64 floats = 46 KB <= 53 KB)
  float* scratch = pl;
  #pragma unroll
  for (int n = 0; n < NT; ++n) scratch[(w * NT + n) * 64 + d] = acc[n];
  __syncthreads();
  float* obase = opart + (((size_t)bh * NJC + jc) * NT) * 64;
  for (int i = tid; i < NT * 64; i += 256)
    obase[i] = scratch[i] + scratch[NT * 64 + i] + scratch[2 * NT * 64 + i] + scratch[3 * NT * 64 + i];
}

// ---------------- fill output with broadcast V-mean ----------------
__global__ __launch_bounds__(256) void k_fill(const float* __restrict__ vmean,
                                              float* __restrict__ out) {
  const size_t i = (size_t)blockIdx.x * 256 + threadIdx.x;
  const int d4 = (int)(i & 15);
  const int bh = (int)(i >> 16);
  const float4* vm = (const float4*)(vmean + bh * D_);
  ((float4*)out)[i] = vm[d4];
}

// ---------------- combine partials, scatter into out rows ----------------
__global__ void k_av2(const float* __restrict__ opart,
                      const int* __restrict__ top,
                      float* __restrict__ out) {
  const int bhn = blockIdx.x, bh = bhn / NT, n = bhn % NT;
  const int d = threadIdx.x;
  float acc = 0.f;
  #pragma unroll
  for (int jc = 0; jc < NJC; ++jc)
    acc += opart[(((size_t)bh * NJC + jc) * NT + n) * D_ + d];
  const int qi = top[bh * NT + n];
  out[((size_t)bh * L_ + qi) * D_ + d] = acc;
}

extern "C" void kernel_launch(void* const* d_in, const int* in_sizes, int n_in,
                              void* d_out, int out_size, void* d_ws, size_t ws_size,
                              hipStream_t stream) {
  const float* q    = (const float*)d_in[0];
  const float* k    = (const float*)d_in[1];
  const float* v    = (const float*)d_in[2];
  const int*   samp = (const int*)d_in[3];
  float* out = (float*)d_out;
  char*  ws  = (char*)d_ws;

  float* M     = (float*)ws;                 // 512 KB (dead after k_topk)
  int*   top   = (int*)(ws + 524288);
  float* vmean = (float*)(ws + 532480);
  float* opart = (float*)(ws + 540672);      // 5.9 MB
  float* vpart = M;                          // reuse M after k_topk
  float* scores = out;                       // d_out doubles as 23.6 MB scratch

  hipLaunchKernelGGL(k_m,       dim3(BH * L_ / 4), dim3(256), 0, stream, q, k, samp, M);
  hipLaunchKernelGGL(k_topk,    dim3(BH),          dim3(256), 0, stream, M, top);
  hipLaunchKernelGGL(k_vmean1,  dim3(B_ * 64),     dim3(256), 0, stream, v, vpart);
  hipLaunchKernelGGL(k_vmean2,  dim3(B_),          dim3(512), 0, stream, vpart, vmean);
  hipLaunchKernelGGL(k_scores,  dim3(BH * 16),     dim3(256), 0, stream, q, k, top, scores);
  hipLaunchKernelGGL(k_softmax, dim3(BH * NT),     dim3(256), 0, stream, scores);
  hipLaunchKernelGGL(k_av,      dim3(BH * NJC),    dim3(256), 0, stream, scores, v, opart);
  hipLaunchKernelGGL(k_fill,    dim3(8192),        dim3(256), 0, stream, vmean, out);
  hipLaunchKernelGGL(k_av2,     dim3(BH * NT),     dim3(64),  0, stream, opart, top, out);
}

// Round 7
// 241.378 us; speedup vs baseline: 2.4409x; 1.0406x over previous
//
#include <hip/hip_runtime.h>
#include <math.h>

#define B_   4
#define L_   4096
#define H_   8
#define D_   64
#define SK   45            // sample_k
#define NT   45            // n_top
#define BH   (B_*H_)       // 32
#define SCALE 0.125f       // 1/sqrt(64)
#define NJC  16            // key chunks for attn*V partials (256 keys each)
#define VCH  64            // L-rows per vmean chunk
#define PLD  52            // p_lds row stride (floats)

// ---------------- Phase 1: M[b,h,q] = max_s(QK_s) - mean_s(QK_s) ----------------
// Block = 4 waves, each wave one (b,h,q). XCD-partition swizzle: XCD x = ib%8
// owns bh in {4x..4x+3}; per-XCD K working set = 1 MB -> L2-resident.
// Inner loop: 12 independent gather+dot4 (no cross-lane ops); reduction via one
// LDS transpose (stride-17, conflict-free) + single shuffle tree.
__global__ __launch_bounds__(256) void k_m(const float* __restrict__ q,
                                           const float* __restrict__ k,
                                           const int* __restrict__ samp,
                                           float* __restrict__ M) {
  const int ib  = blockIdx.x;          // 32768 blocks
  const int x   = ib & 7;              // ~XCD
  const int j   = ib >> 13;            // 0..3
  const int bh  = x * 4 + j;
  const int qb  = (ib >> 3) & 1023;
  const int w   = threadIdx.x >> 6;
  const int qi  = qb * 4 + w;
  const int lane = threadIdx.x & 63;
  const int g    = lane >> 4;          // s-group
  const int r    = lane & 15;          // d-quad
  const int b    = bh >> 3, h = bh & 7;
  const int wid  = bh * L_ + qi;

  const float4 qv = ((const float4*)(q + (((size_t)b * L_ + qi) * H_ + h) * D_))[r];
  const int* srow = samp + (size_t)qi * SK;

  // preload all sample indices (independent loads)
  int idx[12];
  #pragma unroll
  for (int i = 0; i < 12; ++i) {
    const int s = 4 * i + g;
    idx[i] = srow[s < SK ? s : SK - 1];   // clamp to stay in-bounds
  }
  // 12 independent gathers + dot4 partials
  float part[12];
  #pragma unroll
  for (int i = 0; i < 12; ++i) {
    const float4 kv = *(const float4*)(k + (((size_t)b * L_ + idx[i]) * H_ + h) * D_ + r * 4);
    part[i] = qv.x * kv.x + qv.y * kv.y + qv.z * kv.z + qv.w * kv.w;
  }

  // transpose partials via LDS: [wave][s][r], stride 17 floats (conflict-free)
  __shared__ float red[4][48][17];
  #pragma unroll
  for (int i = 0; i < 12; ++i) {
    const int s = 4 * i + g;
    if (s < SK) red[w][s][r] = part[i];
  }
  __syncthreads();

  float ps = 0.f;
  if (lane < 48) {
    #pragma unroll
    for (int rr = 0; rr < 16; ++rr) ps += red[w][lane][rr];
  }
  const bool ok = (lane < SK);
  float pm = ok ? ps : -1e30f;
  float pa = ok ? ps : 0.f;
  #pragma unroll
  for (int o = 1; o < 64; o <<= 1) {
    pm = fmaxf(pm, __shfl_xor(pm, o));
    pa += __shfl_xor(pa, o);
  }
  if (lane == 0) M[wid] = pm - pa * (1.0f / SK);
}

// ---------------- Phase 2: top-45 indices of M per (b,h) ----------------
__global__ __launch_bounds__(256) void k_topk(const float* __restrict__ M,
                                              int* __restrict__ top) {
  __shared__ float vals[L_];
  __shared__ float red_v[4];
  __shared__ int   red_i[4];
  const int bh = blockIdx.x;
  const float* Mrow = M + (size_t)bh * L_;
  for (int i = threadIdx.x; i < L_; i += 256) vals[i] = Mrow[i];
  __syncthreads();
  for (int t = 0; t < NT; ++t) {
    float bv = -1e30f; int bi = 0;
    for (int i = threadIdx.x; i < L_; i += 256) {
      const float v = vals[i];
      if (v > bv) { bv = v; bi = i; }
    }
    #pragma unroll
    for (int off = 1; off < 64; off <<= 1) {
      const float ov = __shfl_xor(bv, off);
      const int   oi = __shfl_xor(bi, off);
      if (ov > bv || (ov == bv && oi < bi)) { bv = ov; bi = oi; }
    }
    const int w = threadIdx.x >> 6;
    if ((threadIdx.x & 63) == 0) { red_v[w] = bv; red_i[w] = bi; }
    __syncthreads();
    if (threadIdx.x == 0) {
      #pragma unroll
      for (int j = 1; j < 4; ++j)
        if (red_v[j] > bv || (red_v[j] == bv && red_i[j] < bi)) { bv = red_v[j]; bi = red_i[j]; }
      top[bh * NT + t] = bi;
      vals[bi] = -1e30f;
    }
    __syncthreads();
  }
}

// ---------------- V mean, stage 1 ----------------
__global__ __launch_bounds__(256) void k_vmean1(const float* __restrict__ v,
                                                float* __restrict__ vpart) {
  const int blk = blockIdx.x;
  const int b   = blk >> 6;
  const int c   = blk & 63;
  const int t   = threadIdx.x;
  const int hd4 = t & 127;
  const int p   = t >> 7;
  const float4* base = (const float4*)(v + ((size_t)b * L_ + (size_t)c * VCH) * (H_ * D_)) + hd4;
  float4 acc = {0.f, 0.f, 0.f, 0.f};
  for (int l = p; l < VCH; l += 2) {
    const float4 x = base[(size_t)l * 128];
    acc.x += x.x; acc.y += x.y; acc.z += x.z; acc.w += x.w;
  }
  __shared__ float4 s[2][128];
  s[p][hd4] = acc;
  __syncthreads();
  if (t < 128) {
    const float4 a = s[0][t], b2 = s[1][t];
    const float4 r = {a.x + b2.x, a.y + b2.y, a.z + b2.z, a.w + b2.w};
    ((float4*)vpart)[(size_t)blk * 128 + t] = r;
  }
}

// ---------------- V mean, stage 2 ----------------
__global__ __launch_bounds__(512) void k_vmean2(const float* __restrict__ vpart,
                                                float* __restrict__ vmean) {
  const int b = blockIdx.x, t = threadIdx.x;
  float acc = 0.f;
  for (int c = 0; c < 64; ++c)
    acc += vpart[((size_t)(b * 64 + c)) * 512 + t];
  vmean[b * 512 + t] = acc * (1.0f / L_);
}

// ---------------- scores = (Q_top @ K^T) * scale ----------------
__global__ __launch_bounds__(256) void k_scores(const float* __restrict__ q,
                                                const float* __restrict__ k,
                                                const int* __restrict__ top,
                                                float* __restrict__ scores) {
  __shared__ float k_lds[256 * 65];
  __shared__ __align__(16) float q_lds[NT * D_];
  const int bh = blockIdx.x >> 4, kb = blockIdx.x & 15;
  const int b = bh >> 3, h = bh & 7;

  const float* kbase = k + (((size_t)b * L_ + kb * 256) * H_ + h) * D_;
  for (int fi = threadIdx.x; fi < 4096; fi += 256) {
    const int j = fi >> 4, d4 = fi & 15;
    const float4 kv = *(const float4*)(kbase + (size_t)j * H_ * D_ + d4 * 4);
    float* dst = &k_lds[j * 65 + d4 * 4];
    dst[0] = kv.x; dst[1] = kv.y; dst[2] = kv.z; dst[3] = kv.w;
  }
  for (int fi = threadIdx.x; fi < NT * D_; fi += 256) {
    const int n = fi >> 6, d = fi & 63;
    const int qi = top[bh * NT + n];
    q_lds[fi] = q[(((size_t)b * L_ + qi) * H_ + h) * D_ + d];
  }
  __syncthreads();

  const int w = threadIdx.x >> 6, lane = threadIdx.x & 63;
  const int jl = w * 64 + lane;
  const int jj = kb * 256 + jl;
  const float* krow = &k_lds[jl * 65];
  for (int n = 0; n < NT; ++n) {
    float acc = 0.f;
    #pragma unroll
    for (int d4 = 0; d4 < 16; ++d4) {
      const float4 qq = *(const float4*)&q_lds[n * 64 + d4 * 4];
      acc += qq.x * krow[d4 * 4 + 0] + qq.y * krow[d4 * 4 + 1]
           + qq.z * krow[d4 * 4 + 2] + qq.w * krow[d4 * 4 + 3];
    }
    scores[((size_t)bh * NT + n) * L_ + jj] = acc * SCALE;
  }
}

// ---------------- row softmax over 4096, in place ----------------
__global__ __launch_bounds__(256) void k_softmax(float* __restrict__ scores) {
  __shared__ float buf[L_];
  __shared__ float red[4];
  const size_t base = (size_t)blockIdx.x * L_;
  float lm = -1e30f;
  for (int i = threadIdx.x; i < L_; i += 256) {
    const float v = scores[base + i];
    buf[i] = v;
    lm = fmaxf(lm, v);
  }
  #pragma unroll
  for (int o = 1; o < 64; o <<= 1) lm = fmaxf(lm, __shfl_xor(lm, o));
  if ((threadIdx.x & 63) == 0) red[threadIdx.x >> 6] = lm;
  __syncthreads();
  const float m = fmaxf(fmaxf(red[0], red[1]), fmaxf(red[2], red[3]));
  float ls = 0.f;
  for (int i = threadIdx.x; i < L_; i += 256) {
    const float p = __expf(buf[i] - m);
    buf[i] = p;
    ls += p;
  }
  #pragma unroll
  for (int o = 1; o < 64; o <<= 1) ls += __shfl_xor(ls, o);
  __syncthreads();
  if ((threadIdx.x & 63) == 0) red[threadIdx.x >> 6] = ls;
  __syncthreads();
  const float inv = 1.0f / (red[0] + red[1] + red[2] + red[3]);
  for (int i = threadIdx.x; i < L_; i += 256) scores[base + i] = buf[i] * inv;
}

// ---------------- attn @ V, key-chunk partials (LDS-staged p) ----------------
__global__ __launch_bounds__(256) void k_av(const float* __restrict__ p,
                                            const float* __restrict__ v,
                                            float* __restrict__ opart) {
  __shared__ __align__(16) float pl[256 * PLD];
  const int bh = blockIdx.x >> 4, jc = blockIdx.x & 15;
  const int b = bh >> 3, h = bh & 7;
  const int tid = threadIdx.x;

  const float* pbase = p + (size_t)bh * NT * L_ + jc * 256;
  for (int fi = tid; fi < NT * 256; fi += 256) {
    const int n = fi >> 8, j = fi & 255;
    pl[j * PLD + n] = pbase[(size_t)n * L_ + j];
  }
  __syncthreads();

  const int w = tid >> 6, d = tid & 63;
  float acc[NT];
  #pragma unroll
  for (int n = 0; n < NT; ++n) acc[n] = 0.f;

  const float* vbase = v + (((size_t)b * L_ + jc * 256 + w * 64) * H_ + h) * D_ + d;
  for (int jl = 0; jl < 64; ++jl) {
    const float vv = vbase[(size_t)jl * (H_ * D_)];
    const float* pr = &pl[(w * 64 + jl) * PLD];
    #pragma unroll
    for (int n4 = 0; n4 < 11; ++n4) {
      const float4 pv = *(const float4*)(pr + n4 * 4);
      acc[n4 * 4 + 0] += pv.x * vv;
      acc[n4 * 4 + 1] += pv.y * vv;
      acc[n4 * 4 + 2] += pv.z * vv;
      acc[n4 * 4 + 3] += pv.w * vv;
    }
    acc[44] += pr[44] * vv;
  }
  __syncthreads();

  float* scratch = pl;
  #pragma unroll
  for (int n = 0; n < NT; ++n) scratch[(w * NT + n) * 64 + d] = acc[n];
  __syncthreads();
  float* obase = opart + (((size_t)bh * NJC + jc) * NT) * 64;
  for (int i = tid; i < NT * 64; i += 256)
    obase[i] = scratch[i] + scratch[NT * 64 + i] + scratch[2 * NT * 64 + i] + scratch[3 * NT * 64 + i];
}

// ---------------- fill output with broadcast V-mean ----------------
__global__ __launch_bounds__(256) void k_fill(const float* __restrict__ vmean,
                                              float* __restrict__ out) {
  const size_t i = (size_t)blockIdx.x * 256 + threadIdx.x;
  const int d4 = (int)(i & 15);
  const int bh = (int)(i >> 16);
  const float4* vm = (const float4*)(vmean + bh * D_);
  ((float4*)out)[i] = vm[d4];
}

// ---------------- combine partials, scatter into out rows ----------------
__global__ void k_av2(const float* __restrict__ opart,
                      const int* __restrict__ top,
                      float* __restrict__ out) {
  const int bhn = blockIdx.x, bh = bhn / NT, n = bhn % NT;
  const int d = threadIdx.x;
  float acc = 0.f;
  #pragma unroll
  for (int jc = 0; jc < NJC; ++jc)
    acc += opart[(((size_t)bh * NJC + jc) * NT + n) * D_ + d];
  const int qi = top[bh * NT + n];
  out[((size_t)bh * L_ + qi) * D_ + d] = acc;
}

extern "C" void kernel_launch(void* const* d_in, const int* in_sizes, int n_in,
                              void* d_out, int out_size, void* d_ws, size_t ws_size,
                              hipStream_t stream) {
  const float* q    = (const float*)d_in[0];
  const float* k    = (const float*)d_in[1];
  const float* v    = (const float*)d_in[2];
  const int*   samp = (const int*)d_in[3];
  float* out = (float*)d_out;
  char*  ws  = (char*)d_ws;

  float* M     = (float*)ws;                 // 512 KB (dead after k_topk)
  int*   top   = (int*)(ws + 524288);
  float* vmean = (float*)(ws + 532480);
  float* opart = (float*)(ws + 540672);      // 5.9 MB
  float* vpart = M;                          // reuse M after k_topk
  float* scores = out;                       // d_out doubles as 23.6 MB scratch

  hipLaunchKernelGGL(k_m,       dim3(BH * L_ / 4), dim3(256), 0, stream, q, k, samp, M);
  hipLaunchKernelGGL(k_topk,    dim3(BH),          dim3(256), 0, stream, M, top);
  hipLaunchKernelGGL(k_vmean1,  dim3(B_ * 64),     dim3(256), 0, stream, v, vpart);
  hipLaunchKernelGGL(k_vmean2,  dim3(B_),          dim3(512), 0, stream, vpart, vmean);
  hipLaunchKernelGGL(k_scores,  dim3(BH * 16),     dim3(256), 0, stream, q, k, top, scores);
  hipLaunchKernelGGL(k_softmax, dim3(BH * NT),     dim3(256), 0, stream, scores);
  hipLaunchKernelGGL(k_av,      dim3(BH * NJC),    dim3(256), 0, stream, scores, v, opart);
  hipLaunchKernelGGL(k_fill,    dim3(8192),        dim3(256), 0, stream, vmean, out);
  hipLaunchKernelGGL(k_av2,     dim3(BH * NT),     dim3(64),  0, stream, opart, top, out);
}

// Round 9
// 238.732 us; speedup vs baseline: 2.4680x; 1.0111x over previous
//
#include <hip/hip_runtime.h>
#include <math.h>

#define B_   4
#define L_   4096
#define H_   8
#define D_   64
#define SK   45            // sample_k
#define NT   45            // n_top
#define BH   (B_*H_)       // 32
#define SCALE 0.125f       // 1/sqrt(64)
#define NJC  16            // key chunks for attn*V partials (256 keys each)
#define VCH  64            // L-rows per vmean chunk
#define PLD  52            // p_lds row stride (floats)

typedef float vfloat4 __attribute__((ext_vector_type(4)));

// ---------------- Phase 1: M[b,h,q] = max_s(QK_s) - mean_s(QK_s) ----------------
// index_sample is shared across (b,h): for one qi, rows K[b, idx, h0..h0+3, :]
// are 1KB contiguous. Wave = (b, h-half, qi); lane = (hg, r). Per row: one
// coalesced 1KB load from wave-uniform base (idx via scalar loads), dot4,
// 16-lane reduce = 2 DPP quad-perm adds + 2 ds_swizzle xors. No LDS storage.
// XCD partition: ib&7 -> (b,half); per-XCD K slice = 4MB ~ L2.
__global__ __launch_bounds__(256) void k_m(const float* __restrict__ q,
                                           const float* __restrict__ k,
                                           const int* __restrict__ samp,
                                           float* __restrict__ M) {
  const int ib   = blockIdx.x;            // 8192 blocks
  const int x    = ib & 7;
  const int b    = x >> 1;
  const int half = x & 1;
  const int w    = threadIdx.x >> 6;
  const int qi   = (ib >> 3) * 4 + w;
  const int lane = threadIdx.x & 63;
  const int hg   = lane >> 4;             // h = half*4 + hg
  const int r    = lane & 15;             // d-quad

  // Q fragment (nontemporal: streamed once, don't pollute K's L2 set)
  const vfloat4* qp = (const vfloat4*)(q + (((size_t)b * L_ + qi) * H_ + half * 4 + hg) * D_) + r;
  const vfloat4 qv = __builtin_nontemporal_load(qp);

  const int qiu = __builtin_amdgcn_readfirstlane(qi);
  const int* srow = samp + (size_t)qiu * SK;          // uniform -> s_load
  const float* kb = k + (size_t)b * L_ * H_ * D_ + half * 4 * D_;  // uniform
  const int loff = hg * D_ + r * 4;                   // per-lane float offset

  float gmax = -1e30f, gsum = 0.f;
  #pragma unroll 9
  for (int s = 0; s < SK; ++s) {
    const int id = srow[s];                           // scalar load (uniform)
    const vfloat4 kv = *(const vfloat4*)(kb + (size_t)id * (H_ * D_) + loff);
    float p = qv.x * kv.x + qv.y * kv.y + qv.z * kv.z + qv.w * kv.w;
    // reduce across 16 lanes (same hg): xor1, xor2 via DPP; xor4, xor8 via swizzle
    { int t = __builtin_amdgcn_mov_dpp(__float_as_int(p), 0xB1, 0xf, 0xf, true); p += __int_as_float(t); }
    { int t = __builtin_amdgcn_mov_dpp(__float_as_int(p), 0x4E, 0xf, 0xf, true); p += __int_as_float(t); }
    { int t = __builtin_amdgcn_ds_swizzle(__float_as_int(p), 0x101F); p += __int_as_float(t); }
    { int t = __builtin_amdgcn_ds_swizzle(__float_as_int(p), 0x201F); p += __int_as_float(t); }
    gmax = fmaxf(gmax, p);
    gsum += p;
  }
  if (r == 0) M[((size_t)b * 8 + half * 4 + hg) * L_ + qi] = gmax - gsum * (1.0f / SK);
}

// ---------------- Phase 2: top-45 indices of M per (b,h) ----------------
__global__ __launch_bounds__(256) void k_topk(const float* __restrict__ M,
                                              int* __restrict__ top) {
  __shared__ float vals[L_];
  __shared__ float red_v[4];
  __shared__ int   red_i[4];
  const int bh = blockIdx.x;
  const float* Mrow = M + (size_t)bh * L_;
  for (int i = threadIdx.x; i < L_; i += 256) vals[i] = Mrow[i];
  __syncthreads();
  for (int t = 0; t < NT; ++t) {
    float bv = -1e30f; int bi = 0;
    for (int i = threadIdx.x; i < L_; i += 256) {
      const float v = vals[i];
      if (v > bv) { bv = v; bi = i; }
    }
    #pragma unroll
    for (int off = 1; off < 64; off <<= 1) {
      const float ov = __shfl_xor(bv, off);
      const int   oi = __shfl_xor(bi, off);
      if (ov > bv || (ov == bv && oi < bi)) { bv = ov; bi = oi; }
    }
    const int w = threadIdx.x >> 6;
    if ((threadIdx.x & 63) == 0) { red_v[w] = bv; red_i[w] = bi; }
    __syncthreads();
    if (threadIdx.x == 0) {
      #pragma unroll
      for (int j = 1; j < 4; ++j)
        if (red_v[j] > bv || (red_v[j] == bv && red_i[j] < bi)) { bv = red_v[j]; bi = red_i[j]; }
      top[bh * NT + t] = bi;
      vals[bi] = -1e30f;
    }
    __syncthreads();
  }
}

// ---------------- V mean, stage 1 ----------------
__global__ __launch_bounds__(256) void k_vmean1(const float* __restrict__ v,
                                                float* __restrict__ vpart) {
  const int blk = blockIdx.x;
  const int b   = blk >> 6;
  const int c   = blk & 63;
  const int t   = threadIdx.x;
  const int hd4 = t & 127;
  const int p   = t >> 7;
  const float4* base = (const float4*)(v + ((size_t)b * L_ + (size_t)c * VCH) * (H_ * D_)) + hd4;
  float4 acc = {0.f, 0.f, 0.f, 0.f};
  for (int l = p; l < VCH; l += 2) {
    const float4 x = base[(size_t)l * 128];
    acc.x += x.x; acc.y += x.y; acc.z += x.z; acc.w += x.w;
  }
  __shared__ float4 s[2][128];
  s[p][hd4] = acc;
  __syncthreads();
  if (t < 128) {
    const float4 a = s[0][t], b2 = s[1][t];
    const float4 r = {a.x + b2.x, a.y + b2.y, a.z + b2.z, a.w + b2.w};
    ((float4*)vpart)[(size_t)blk * 128 + t] = r;
  }
}

// ---------------- V mean, stage 2 ----------------
__global__ __launch_bounds__(512) void k_vmean2(const float* __restrict__ vpart,
                                                float* __restrict__ vmean) {
  const int b = blockIdx.x, t = threadIdx.x;
  float acc = 0.f;
  for (int c = 0; c < 64; ++c)
    acc += vpart[((size_t)(b * 64 + c)) * 512 + t];
  vmean[b * 512 + t] = acc * (1.0f / L_);
}

// ---------------- scores = (Q_top @ K^T) * scale ----------------
__global__ __launch_bounds__(256) void k_scores(const float* __restrict__ q,
                                                const float* __restrict__ k,
                                                const int* __restrict__ top,
                                                float* __restrict__ scores) {
  __shared__ float k_lds[256 * 65];
  __shared__ __align__(16) float q_lds[NT * D_];
  const int bh = blockIdx.x >> 4, kb = blockIdx.x & 15;
  const int b = bh >> 3, h = bh & 7;

  const float* kbase = k + (((size_t)b * L_ + kb * 256) * H_ + h) * D_;
  for (int fi = threadIdx.x; fi < 4096; fi += 256) {
    const int j = fi >> 4, d4 = fi & 15;
    const float4 kv = *(const float4*)(kbase + (size_t)j * H_ * D_ + d4 * 4);
    float* dst = &k_lds[j * 65 + d4 * 4];
    dst[0] = kv.x; dst[1] = kv.y; dst[2] = kv.z; dst[3] = kv.w;
  }
  for (int fi = threadIdx.x; fi < NT * D_; fi += 256) {
    const int n = fi >> 6, d = fi & 63;
    const int qi = top[bh * NT + n];
    q_lds[fi] = q[(((size_t)b * L_ + qi) * H_ + h) * D_ + d];
  }
  __syncthreads();

  const int w = threadIdx.x >> 6, lane = threadIdx.x & 63;
  const int jl = w * 64 + lane;
  const int jj = kb * 256 + jl;
  const float* krow = &k_lds[jl * 65];
  for (int n = 0; n < NT; ++n) {
    float acc = 0.f;
    #pragma unroll
    for (int d4 = 0; d4 < 16; ++d4) {
      const float4 qq = *(const float4*)&q_lds[n * 64 + d4 * 4];
      acc += qq.x * krow[d4 * 4 + 0] + qq.y * krow[d4 * 4 + 1]
           + qq.z * krow[d4 * 4 + 2] + qq.w * krow[d4 * 4 + 3];
    }
    scores[((size_t)bh * NT + n) * L_ + jj] = acc * SCALE;
  }
}

// ---------------- row softmax over 4096, in place ----------------
__global__ __launch_bounds__(256) void k_softmax(float* __restrict__ scores) {
  __shared__ float buf[L_];
  __shared__ float red[4];
  const size_t base = (size_t)blockIdx.x * L_;
  float lm = -1e30f;
  for (int i = threadIdx.x; i < L_; i += 256) {
    const float v = scores[base + i];
    buf[i] = v;
    lm = fmaxf(lm, v);
  }
  #pragma unroll
  for (int o = 1; o < 64; o <<= 1) lm = fmaxf(lm, __shfl_xor(lm, o));
  if ((threadIdx.x & 63) == 0) red[threadIdx.x >> 6] = lm;
  __syncthreads();
  const float m = fmaxf(fmaxf(red[0], red[1]), fmaxf(red[2], red[3]));
  float ls = 0.f;
  for (int i = threadIdx.x; i < L_; i += 256) {
    const float p = __expf(buf[i] - m);
    buf[i] = p;
    ls += p;
  }
  #pragma unroll
  for (int o = 1; o < 64; o <<= 1) ls += __shfl_xor(ls, o);
  __syncthreads();
  if ((threadIdx.x & 63) == 0) red[threadIdx.x >> 6] = ls;
  __syncthreads();
  const float inv = 1.0f / (red[0] + red[1] + red[2] + red[3]);
  for (int i = threadIdx.x; i < L_; i += 256) scores[base + i] = buf[i] * inv;
}

// ---------------- attn @ V, key-chunk partials (LDS-staged p) ----------------
__global__ __launch_bounds__(256) void k_av(const float* __restrict__ p,
                                            const float* __restrict__ v,
                                            float* __restrict__ opart) {
  __shared__ __align__(16) float pl[256 * PLD];
  const int bh = blockIdx.x >> 4, jc = blockIdx.x & 15;
  const int b = bh >> 3, h = bh & 7;
  const int tid = threadIdx.x;

  const float* pbase = p + (size_t)bh * NT * L_ + jc * 256;
  for (int fi = tid; fi < NT * 256; fi += 256) {
    const int n = fi >> 8, j = fi & 255;
    pl[j * PLD + n] = pbase[(size_t)n * L_ + j];
  }
  __syncthreads();

  const int w = tid >> 6, d = tid & 63;
  float acc[NT];
  #pragma unroll
  for (int n = 0; n < NT; ++n) acc[n] = 0.f;

  const float* vbase = v + (((size_t)b * L_ + jc * 256 + w * 64) * H_ + h) * D_ + d;
  for (int jl = 0; jl < 64; ++jl) {
    const float vv = vbase[(size_t)jl * (H_ * D_)];
    const float* pr = &pl[(w * 64 + jl) * PLD];
    #pragma unroll
    for (int n4 = 0; n4 < 11; ++n4) {
      const float4 pv = *(const float4*)(pr + n4 * 4);
      acc[n4 * 4 + 0] += pv.x * vv;
      acc[n4 * 4 + 1] += pv.y * vv;
      acc[n4 * 4 + 2] += pv.z * vv;
      acc[n4 * 4 + 3] += pv.w * vv;
    }
    acc[44] += pr[44] * vv;
  }
  __syncthreads();

  float* scratch = pl;
  #pragma unroll
  for (int n = 0; n < NT; ++n) scratch[(w * NT + n) * 64 + d] = acc[n];
  __syncthreads();
  float* obase = opart + (((size_t)bh * NJC + jc) * NT) * 64;
  for (int i = tid; i < NT * 64; i += 256)
    obase[i] = scratch[i] + scratch[NT * 64 + i] + scratch[2 * NT * 64 + i] + scratch[3 * NT * 64 + i];
}

// ---------------- fill output with broadcast V-mean ----------------
__global__ __launch_bounds__(256) void k_fill(const float* __restrict__ vmean,
                                              float* __restrict__ out) {
  const size_t i = (size_t)blockIdx.x * 256 + threadIdx.x;
  const int d4 = (int)(i & 15);
  const int bh = (int)(i >> 16);
  const float4* vm = (const float4*)(vmean + bh * D_);
  ((float4*)out)[i] = vm[d4];
}

// ---------------- combine partials, scatter into out rows ----------------
__global__ void k_av2(const float* __restrict__ opart,
                      const int* __restrict__ top,
                      float* __restrict__ out) {
  const int bhn = blockIdx.x, bh = bhn / NT, n = bhn % NT;
  const int d = threadIdx.x;
  float acc = 0.f;
  #pragma unroll
  for (int jc = 0; jc < NJC; ++jc)
    acc += opart[(((size_t)bh * NJC + jc) * NT + n) * D_ + d];
  const int qi = top[bh * NT + n];
  out[((size_t)bh * L_ + qi) * D_ + d] = acc;
}

extern "C" void kernel_launch(void* const* d_in, const int* in_sizes, int n_in,
                              void* d_out, int out_size, void* d_ws, size_t ws_size,
                              hipStream_t stream) {
  const float* q    = (const float*)d_in[0];
  const float* k    = (const float*)d_in[1];
  const float* v    = (const float*)d_in[2];
  const int*   samp = (const int*)d_in[3];
  float* out = (float*)d_out;
  char*  ws  = (char*)d_ws;

  float* M     = (float*)ws;                 // 512 KB (dead after k_topk)
  int*   top   = (int*)(ws + 524288);
  float* vmean = (float*)(ws + 532480);
  float* opart = (float*)(ws + 540672);      // 5.9 MB
  float* vpart = M;                          // reuse M after k_topk
  float* scores = out;                       // d_out doubles as 23.6 MB scratch

  hipLaunchKernelGGL(k_m,       dim3(BH * L_ / 16), dim3(256), 0, stream, q, k, samp, M);  // 8192
  hipLaunchKernelGGL(k_topk,    dim3(BH),          dim3(256), 0, stream, M, top);
  hipLaunchKernelGGL(k_vmean1,  dim3(B_ * 64),     dim3(256), 0, stream, v, vpart);
  hipLaunchKernelGGL(k_vmean2,  dim3(B_),          dim3(512), 0, stream, vpart, vmean);
  hipLaunchKernelGGL(k_scores,  dim3(BH * 16),     dim3(256), 0, stream, q, k, top, scores);
  hipLaunchKernelGGL(k_softmax, dim3(BH * NT),     dim3(256), 0, stream, scores);
  hipLaunchKernelGGL(k_av,      dim3(BH * NJC),    dim3(256), 0, stream, scores, v, opart);
  hipLaunchKernelGGL(k_fill,    dim3(8192),        dim3(256), 0, stream, vmean, out);
  hipLaunchKernelGGL(k_av2,     dim3(BH * NT),     dim3(64),  0, stream, opart, top, out);
}

// Round 10
// 182.118 us; speedup vs baseline: 3.2352x; 1.3109x over previous
//
#include <hip/hip_runtime.h>
#include <math.h>

#define B_   4
#define L_   4096
#define H_   8
#define D_   64
#define SK   45            // sample_k
#define NT   45            // n_top
#define BH   (B_*H_)       // 32
#define SCALE 0.125f       // 1/sqrt(64)
#define NJC  16            // key chunks for attn*V partials (256 keys each)
#define VCH  64            // L-rows per vmean chunk
#define PLD  52            // p_lds row stride (floats)

typedef float vfloat4 __attribute__((ext_vector_type(4)));

// ---------------- Phase 1: M[b,h,q] = max_s(QK_s) - mean_s(QK_s) ----------------
// index_sample is shared across (b,h): for one qi, rows K[b, idx, h0..h0+3, :]
// are 1KB contiguous. Wave = (b, h-half, qi); lane = (hg, r). Per row: one
// coalesced 1KB load from wave-uniform base (idx via scalar loads), dot4,
// 16-lane reduce = 2 DPP quad-perm adds + 2 ds_swizzle xors. No LDS storage.
// XCD partition: ib&7 -> (b,half); per-XCD K slice = 4MB ~ L2.
__global__ __launch_bounds__(256) void k_m(const float* __restrict__ q,
                                           const float* __restrict__ k,
                                           const int* __restrict__ samp,
                                           float* __restrict__ M) {
  const int ib   = blockIdx.x;            // 8192 blocks
  const int x    = ib & 7;
  const int b    = x >> 1;
  const int half = x & 1;
  const int w    = threadIdx.x >> 6;
  const int qi   = (ib >> 3) * 4 + w;
  const int lane = threadIdx.x & 63;
  const int hg   = lane >> 4;             // h = half*4 + hg
  const int r    = lane & 15;             // d-quad

  const vfloat4* qp = (const vfloat4*)(q + (((size_t)b * L_ + qi) * H_ + half * 4 + hg) * D_) + r;
  const vfloat4 qv = __builtin_nontemporal_load(qp);

  const int qiu = __builtin_amdgcn_readfirstlane(qi);
  const int* srow = samp + (size_t)qiu * SK;          // uniform -> s_load
  const float* kb = k + (size_t)b * L_ * H_ * D_ + half * 4 * D_;  // uniform
  const int loff = hg * D_ + r * 4;                   // per-lane float offset

  float gmax = -1e30f, gsum = 0.f;
  #pragma unroll 9
  for (int s = 0; s < SK; ++s) {
    const int id = srow[s];                           // scalar load (uniform)
    const vfloat4 kv = *(const vfloat4*)(kb + (size_t)id * (H_ * D_) + loff);
    float p = qv.x * kv.x + qv.y * kv.y + qv.z * kv.z + qv.w * kv.w;
    { int t = __builtin_amdgcn_mov_dpp(__float_as_int(p), 0xB1, 0xf, 0xf, true); p += __int_as_float(t); }
    { int t = __builtin_amdgcn_mov_dpp(__float_as_int(p), 0x4E, 0xf, 0xf, true); p += __int_as_float(t); }
    { int t = __builtin_amdgcn_ds_swizzle(__float_as_int(p), 0x101F); p += __int_as_float(t); }
    { int t = __builtin_amdgcn_ds_swizzle(__float_as_int(p), 0x201F); p += __int_as_float(t); }
    gmax = fmaxf(gmax, p);
    gsum += p;
  }
  if (r == 0) M[((size_t)b * 8 + half * 4 + hg) * L_ + qi] = gmax - gsum * (1.0f / SK);
}

// ---------------- Phase 2: top-45 of M per (b,h) via radix select ----------------
// Keys: monotonic u32 transform of f32. 4 MSB->LSB byte passes (histogram +
// block suffix-scan + byte pick), then compaction: all > T (any order) plus
// lowest-index `remaining` == T (ordered block prefix scan). Exact same index
// SET as top_k with lowest-index tie-break.
__global__ __launch_bounds__(256) void k_topk(const float* __restrict__ M,
                                              int* __restrict__ top) {
  __shared__ unsigned keys[L_];        // 16 KB
  __shared__ unsigned hist[256];
  __shared__ unsigned wsum[4];
  __shared__ int sByte;
  __shared__ unsigned sAbove;
  __shared__ int cnt;
  const int bh = blockIdx.x, tid = threadIdx.x;
  const float* Mrow = M + (size_t)bh * L_;
  for (int i = tid; i < L_; i += 256) {
    const unsigned u = __float_as_uint(Mrow[i]);
    keys[i] = (u & 0x80000000u) ? ~u : (u | 0x80000000u);
  }
  unsigned prefix = 0u, fixed = 0u;
  unsigned remaining = NT;
  for (int p = 3; p >= 0; --p) {
    hist[tid] = 0u;
    __syncthreads();
    const int sh = p * 8;
    for (int i = tid; i < L_; i += 256) {
      const unsigned kk = keys[i];
      if ((kk & fixed) == prefix) atomicAdd(&hist[(kk >> sh) & 0xFFu], 1u);
    }
    __syncthreads();
    const int c = 255 - tid;                   // thread t owns bin 255-t
    const unsigned v = hist[c];
    unsigned x = v;                            // inclusive scan over t => suffix sum over c
    #pragma unroll
    for (int o = 1; o < 64; o <<= 1) {
      const unsigned y = __shfl_up(x, o);
      if ((tid & 63) >= o) x += y;
    }
    if ((tid & 63) == 63) wsum[tid >> 6] = x;
    __syncthreads();
    unsigned off = 0;
    for (int w2 = 0; w2 < (tid >> 6); ++w2) off += wsum[w2];
    const unsigned Sincl = x + off;            // count(key byte >= c | prefix match)
    const unsigned Sab   = Sincl - v;          // count(key byte >  c | prefix match)
    if (Sab < remaining && remaining <= Sincl) { sByte = c; sAbove = Sab; }
    __syncthreads();
    prefix |= (unsigned)sByte << sh;
    fixed  |= 0xFFu << sh;
    remaining -= sAbove;
    __syncthreads();
  }
  // prefix == key of the NT-th largest (threshold T)
  if (tid == 0) cnt = 0;
  __syncthreads();
  int* trow = top + bh * NT;
  for (int i = tid; i < L_; i += 256) {
    if (keys[i] > prefix) { const int s = atomicAdd(&cnt, 1); trow[s] = i; }
  }
  __syncthreads();
  const int ngt = cnt;                         // == NT - remaining
  // ties: lowest-index `remaining` keys == T, via ordered prefix scan
  const int base = tid * 16;
  int lc = 0;
  #pragma unroll
  for (int j = 0; j < 16; ++j) lc += (keys[base + j] == prefix);
  unsigned x2 = (unsigned)lc;
  #pragma unroll
  for (int o = 1; o < 64; o <<= 1) {
    const unsigned y = __shfl_up(x2, o);
    if ((tid & 63) >= o) x2 += y;
  }
  if ((tid & 63) == 63) wsum[tid >> 6] = x2;
  __syncthreads();
  unsigned off2 = 0;
  for (int w2 = 0; w2 < (tid >> 6); ++w2) off2 += wsum[w2];
  unsigned rk = (x2 - (unsigned)lc) + off2;    // exclusive rank in index order
  #pragma unroll
  for (int j = 0; j < 16; ++j) {
    if (keys[base + j] == prefix) {
      if (rk < remaining) trow[ngt + (int)rk] = base + j;
      ++rk;
    }
  }
}

// ---------------- V mean, stage 1 ----------------
__global__ __launch_bounds__(256) void k_vmean1(const float* __restrict__ v,
                                                float* __restrict__ vpart) {
  const int blk = blockIdx.x;
  const int b   = blk >> 6;
  const int c   = blk & 63;
  const int t   = threadIdx.x;
  const int hd4 = t & 127;
  const int p   = t >> 7;
  const float4* base = (const float4*)(v + ((size_t)b * L_ + (size_t)c * VCH) * (H_ * D_)) + hd4;
  float4 acc = {0.f, 0.f, 0.f, 0.f};
  for (int l = p; l < VCH; l += 2) {
    const float4 x = base[(size_t)l * 128];
    acc.x += x.x; acc.y += x.y; acc.z += x.z; acc.w += x.w;
  }
  __shared__ float4 s[2][128];
  s[p][hd4] = acc;
  __syncthreads();
  if (t < 128) {
    const float4 a = s[0][t], b2 = s[1][t];
    const float4 r = {a.x + b2.x, a.y + b2.y, a.z + b2.z, a.w + b2.w};
    ((float4*)vpart)[(size_t)blk * 128 + t] = r;
  }
}

// ---------------- V mean, stage 2 ----------------
__global__ __launch_bounds__(512) void k_vmean2(const float* __restrict__ vpart,
                                                float* __restrict__ vmean) {
  const int b = blockIdx.x, t = threadIdx.x;
  float acc = 0.f;
  for (int c = 0; c < 64; ++c)
    acc += vpart[((size_t)(b * 64 + c)) * 512 + t];
  vmean[b * 512 + t] = acc * (1.0f / L_);
}

// ---------------- scores = (Q_top @ K^T) * scale ----------------
__global__ __launch_bounds__(256) void k_scores(const float* __restrict__ q,
                                                const float* __restrict__ k,
                                                const int* __restrict__ top,
                                                float* __restrict__ scores) {
  __shared__ float k_lds[256 * 65];
  __shared__ __align__(16) float q_lds[NT * D_];
  const int bh = blockIdx.x >> 4, kb = blockIdx.x & 15;
  const int b = bh >> 3, h = bh & 7;

  const float* kbase = k + (((size_t)b * L_ + kb * 256) * H_ + h) * D_;
  for (int fi = threadIdx.x; fi < 4096; fi += 256) {
    const int j = fi >> 4, d4 = fi & 15;
    const float4 kv = *(const float4*)(kbase + (size_t)j * H_ * D_ + d4 * 4);
    float* dst = &k_lds[j * 65 + d4 * 4];
    dst[0] = kv.x; dst[1] = kv.y; dst[2] = kv.z; dst[3] = kv.w;
  }
  for (int fi = threadIdx.x; fi < NT * D_; fi += 256) {
    const int n = fi >> 6, d = fi & 63;
    const int qi = top[bh * NT + n];
    q_lds[fi] = q[(((size_t)b * L_ + qi) * H_ + h) * D_ + d];
  }
  __syncthreads();

  const int w = threadIdx.x >> 6, lane = threadIdx.x & 63;
  const int jl = w * 64 + lane;
  const int jj = kb * 256 + jl;
  const float* krow = &k_lds[jl * 65];
  for (int n = 0; n < NT; ++n) {
    float acc = 0.f;
    #pragma unroll
    for (int d4 = 0; d4 < 16; ++d4) {
      const float4 qq = *(const float4*)&q_lds[n * 64 + d4 * 4];
      acc += qq.x * krow[d4 * 4 + 0] + qq.y * krow[d4 * 4 + 1]
           + qq.z * krow[d4 * 4 + 2] + qq.w * krow[d4 * 4 + 3];
    }
    scores[((size_t)bh * NT + n) * L_ + jj] = acc * SCALE;
  }
}

// ---------------- row softmax over 4096, in place ----------------
__global__ __launch_bounds__(256) void k_softmax(float* __restrict__ scores) {
  __shared__ float buf[L_];
  __shared__ float red[4];
  const size_t base = (size_t)blockIdx.x * L_;
  float lm = -1e30f;
  for (int i = threadIdx.x; i < L_; i += 256) {
    const float v = scores[base + i];
    buf[i] = v;
    lm = fmaxf(lm, v);
  }
  #pragma unroll
  for (int o = 1; o < 64; o <<= 1) lm = fmaxf(lm, __shfl_xor(lm, o));
  if ((threadIdx.x & 63) == 0) red[threadIdx.x >> 6] = lm;
  __syncthreads();
  const float m = fmaxf(fmaxf(red[0], red[1]), fmaxf(red[2], red[3]));
  float ls = 0.f;
  for (int i = threadIdx.x; i < L_; i += 256) {
    const float p = __expf(buf[i] - m);
    buf[i] = p;
    ls += p;
  }
  #pragma unroll
  for (int o = 1; o < 64; o <<= 1) ls += __shfl_xor(ls, o);
  __syncthreads();
  if ((threadIdx.x & 63) == 0) red[threadIdx.x >> 6] = ls;
  __syncthreads();
  const float inv = 1.0f / (red[0] + red[1] + red[2] + red[3]);
  for (int i = threadIdx.x; i < L_; i += 256) scores[base + i] = buf[i] * inv;
}

// ---------------- attn @ V, key-chunk partials (LDS-staged p) ----------------
__global__ __launch_bounds__(256) void k_av(const float* __restrict__ p,
                                            const float* __restrict__ v,
                                            float* __restrict__ opart) {
  __shared__ __align__(16) float pl[256 * PLD];
  const int bh = blockIdx.x >> 4, jc = blockIdx.x & 15;
  const int b = bh >> 3, h = bh & 7;
  const int tid = threadIdx.x;

  const float* pbase = p + (size_t)bh * NT * L_ + jc * 256;
  for (int fi = tid; fi < NT * 256; fi += 256) {
    const int n = fi >> 8, j = fi & 255;
    pl[j * PLD + n] = pbase[(size_t)n * L_ + j];
  }
  __syncthreads();

  const int w = tid >> 6, d = tid & 63;
  float acc[NT];
  #pragma unroll
  for (int n = 0; n < NT; ++n) acc[n] = 0.f;

  const float* vbase = v + (((size_t)b * L_ + jc * 256 + w * 64) * H_ + h) * D_ + d;
  for (int jl = 0; jl < 64; ++jl) {
    const float vv = vbase[(size_t)jl * (H_ * D_)];
    const float* pr = &pl[(w * 64 + jl) * PLD];
    #pragma unroll
    for (int n4 = 0; n4 < 11; ++n4) {
      const float4 pv = *(const float4*)(pr + n4 * 4);
      acc[n4 * 4 + 0] += pv.x * vv;
      acc[n4 * 4 + 1] += pv.y * vv;
      acc[n4 * 4 + 2] += pv.z * vv;
      acc[n4 * 4 + 3] += pv.w * vv;
    }
    acc[44] += pr[44] * vv;
  }
  __syncthreads();

  float* scratch = pl;
  #pragma unroll
  for (int n = 0; n < NT; ++n) scratch[(w * NT + n) * 64 + d] = acc[n];
  __syncthreads();
  float* obase = opart + (((size_t)bh * NJC + jc) * NT) * 64;
  for (int i = tid; i < NT * 64; i += 256)
    obase[i] = scratch[i] + scratch[NT * 64 + i] + scratch[2 * NT * 64 + i] + scratch[3 * NT * 64 + i];
}

// ---------------- fill output with broadcast V-mean ----------------
__global__ __launch_bounds__(256) void k_fill(const float* __restrict__ vmean,
                                              float* __restrict__ out) {
  const size_t i = (size_t)blockIdx.x * 256 + threadIdx.x;
  const int d4 = (int)(i & 15);
  const int bh = (int)(i >> 16);
  const float4* vm = (const float4*)(vmean + bh * D_);
  ((float4*)out)[i] = vm[d4];
}

// ---------------- combine partials, scatter into out rows ----------------
__global__ void k_av2(const float* __restrict__ opart,
                      const int* __restrict__ top,
                      float* __restrict__ out) {
  const int bhn = blockIdx.x, bh = bhn / NT, n = bhn % NT;
  const int d = threadIdx.x;
  float acc = 0.f;
  #pragma unroll
  for (int jc = 0; jc < NJC; ++jc)
    acc += opart[(((size_t)bh * NJC + jc) * NT + n) * D_ + d];
  const int qi = top[bh * NT + n];
  out[((size_t)bh * L_ + qi) * D_ + d] = acc;
}

extern "C" void kernel_launch(void* const* d_in, const int* in_sizes, int n_in,
                              void* d_out, int out_size, void* d_ws, size_t ws_size,
                              hipStream_t stream) {
  const float* q    = (const float*)d_in[0];
  const float* k    = (const float*)d_in[1];
  const float* v    = (const float*)d_in[2];
  const int*   samp = (const int*)d_in[3];
  float* out = (float*)d_out;
  char*  ws  = (char*)d_ws;

  float* M     = (float*)ws;                 // 512 KB (dead after k_topk)
  int*   top   = (int*)(ws + 524288);
  float* vmean = (float*)(ws + 532480);
  float* opart = (float*)(ws + 540672);      // 5.9 MB
  float* vpart = M;                          // reuse M after k_topk
  float* scores = out;                       // d_out doubles as 23.6 MB scratch

  hipLaunchKernelGGL(k_m,       dim3(BH * L_ / 16), dim3(256), 0, stream, q, k, samp, M);  // 8192
  hipLaunchKernelGGL(k_topk,    dim3(BH),          dim3(256), 0, stream, M, top);
  hipLaunchKernelGGL(k_vmean1,  dim3(B_ * 64),     dim3(256), 0, stream, v, vpart);
  hipLaunchKernelGGL(k_vmean2,  dim3(B_),          dim3(512), 0, stream, vpart, vmean);
  hipLaunchKernelGGL(k_scores,  dim3(BH * 16),     dim3(256), 0, stream, q, k, top, scores);
  hipLaunchKernelGGL(k_softmax, dim3(BH * NT),     dim3(256), 0, stream, scores);
  hipLaunchKernelGGL(k_av,      dim3(BH * NJC),    dim3(256), 0, stream, scores, v, opart);
  hipLaunchKernelGGL(k_fill,    dim3(8192),        dim3(256), 0, stream, vmean, out);
  hipLaunchKernelGGL(k_av2,     dim3(BH * NT),     dim3(64),  0, stream, opart, top, out);
}

// Round 12
// 182.033 us; speedup vs baseline: 3.2367x; 1.0005x over previous
//
#include <hip/hip_runtime.h>
#include <math.h>

#define B_   4
#define L_   4096
#define H_   8
#define D_   64
#define SK   45            // sample_k
#define NT   45            // n_top
#define BH   (B_*H_)       // 32
#define SCALE 0.125f       // 1/sqrt(64)
#define NJC  16            // key chunks for attn*V partials (256 keys each)
#define VCH  64            // L-rows per vmean chunk
#define PLD  52            // p_lds row stride (floats)

typedef float vfloat4 __attribute__((ext_vector_type(4)));

// ---------------- Phase 1: M[b,h,q] = max_s(QK_s) - mean_s(QK_s) ----------------
// Wave = (b, half, qi-pair): 32-lane group = one qi, lane = (hg, r8), 32B/lane.
// Per sample: 1 ds_read id (imm offset), 2 coalesced dwordx4, dot8, 3-step
// DPP-only reduce (quad_perm xor1/xor2 + row_half_mirror) - no LDS pipe.
// XCD partition: ib&7 -> (b,half); per-XCD K slice = 4MB ~ L2.
__global__ __launch_bounds__(256) void k_m(const float* __restrict__ q,
                                           const float* __restrict__ k,
                                           const int* __restrict__ samp,
                                           float* __restrict__ M) {
  __shared__ int sid[8 * SK];             // 360 ids (8 qi per block)
  const int ib   = blockIdx.x;            // 4096 blocks
  const int x    = ib & 7;
  const int b    = x >> 1;
  const int half = x & 1;
  const int qi_base = (ib >> 3) * 8;
  const int tid = threadIdx.x;
  for (int i = tid; i < 8 * SK; i += 256)          // FIX: full staging (360 > 256)
    sid[i] = samp[(size_t)qi_base * SK + i];
  __syncthreads();

  const int w    = tid >> 6;
  const int lane = tid & 63;
  const int g2   = lane >> 5;             // qi sub-group within wave
  const int l32  = lane & 31;
  const int hg   = l32 >> 3;              // head within half
  const int r8   = l32 & 7;               // 8-float chunk
  const int qi   = qi_base + w * 2 + g2;
  const int wq   = w * 2 + g2;

  const float* qbase = q + (((size_t)b * L_ + qi) * H_ + half * 4 + hg) * D_ + r8 * 8;
  const vfloat4 qa = __builtin_nontemporal_load((const vfloat4*)qbase);
  const vfloat4 qb4 = __builtin_nontemporal_load((const vfloat4*)(qbase + 4));

  const int* myids = sid + wq * SK;
  const float* kb2 = k + (size_t)b * L_ * (H_ * D_) + (half * 4 + hg) * D_ + r8 * 8;

  float gmax = -1e30f, gsum = 0.f;
  #pragma unroll 5
  for (int s = 0; s < SK; ++s) {
    const int id = myids[s];              // ds_read_b32, broadcast per group
    const float* kr = kb2 + (size_t)id * (H_ * D_);
    const vfloat4 ka  = *(const vfloat4*)kr;
    const vfloat4 kbv = *(const vfloat4*)(kr + 4);
    float p = qa.x*ka.x + qa.y*ka.y + qa.z*ka.z + qa.w*ka.w
            + qb4.x*kbv.x + qb4.y*kbv.y + qb4.z*kbv.z + qb4.w*kbv.w;
    { int t = __builtin_amdgcn_mov_dpp(__float_as_int(p), 0xB1, 0xf, 0xf, true); p += __int_as_float(t); }  // xor1
    { int t = __builtin_amdgcn_mov_dpp(__float_as_int(p), 0x4E, 0xf, 0xf, true); p += __int_as_float(t); }  // xor2
    { int t = __builtin_amdgcn_mov_dpp(__float_as_int(p), 0x141, 0xf, 0xf, true); p += __int_as_float(t); } // half_mirror
    gmax = fmaxf(gmax, p);
    gsum += p;
  }
  if (r8 == 0) M[((size_t)b * 8 + half * 4 + hg) * L_ + qi] = gmax - gsum * (1.0f / SK);
}

// ---------------- Phase 2: top-45 of M per (b,h) via radix select ----------------
__global__ __launch_bounds__(256) void k_topk(const float* __restrict__ M,
                                              int* __restrict__ top) {
  __shared__ unsigned keys[L_];        // 16 KB
  __shared__ unsigned hist[256];
  __shared__ unsigned wsum[4];
  __shared__ int sByte;
  __shared__ unsigned sAbove;
  __shared__ int cnt;
  const int bh = blockIdx.x, tid = threadIdx.x;
  const float* Mrow = M + (size_t)bh * L_;
  for (int i = tid; i < L_; i += 256) {
    const unsigned u = __float_as_uint(Mrow[i]);
    keys[i] = (u & 0x80000000u) ? ~u : (u | 0x80000000u);
  }
  unsigned prefix = 0u, fixed = 0u;
  unsigned remaining = NT;
  for (int p = 3; p >= 0; --p) {
    hist[tid] = 0u;
    __syncthreads();
    const int sh = p * 8;
    for (int i = tid; i < L_; i += 256) {
      const unsigned kk = keys[i];
      if ((kk & fixed) == prefix) atomicAdd(&hist[(kk >> sh) & 0xFFu], 1u);
    }
    __syncthreads();
    const int c = 255 - tid;                   // thread t owns bin 255-t
    const unsigned v = hist[c];
    unsigned x = v;                            // inclusive scan over t => suffix sum over c
    #pragma unroll
    for (int o = 1; o < 64; o <<= 1) {
      const unsigned y = __shfl_up(x, o);
      if ((tid & 63) >= o) x += y;
    }
    if ((tid & 63) == 63) wsum[tid >> 6] = x;
    __syncthreads();
    unsigned off = 0;
    for (int w2 = 0; w2 < (tid >> 6); ++w2) off += wsum[w2];
    const unsigned Sincl = x + off;            // count(key byte >= c | prefix match)
    const unsigned Sab   = Sincl - v;          // count(key byte >  c | prefix match)
    if (Sab < remaining && remaining <= Sincl) { sByte = c; sAbove = Sab; }
    __syncthreads();
    prefix |= (unsigned)sByte << sh;
    fixed  |= 0xFFu << sh;
    remaining -= sAbove;
    __syncthreads();
  }
  if (tid == 0) cnt = 0;
  __syncthreads();
  int* trow = top + bh * NT;
  for (int i = tid; i < L_; i += 256) {
    if (keys[i] > prefix) { const int s = atomicAdd(&cnt, 1); trow[s] = i; }
  }
  __syncthreads();
  const int ngt = cnt;                         // == NT - remaining
  const int base = tid * 16;
  int lc = 0;
  #pragma unroll
  for (int j = 0; j < 16; ++j) lc += (keys[base + j] == prefix);
  unsigned x2 = (unsigned)lc;
  #pragma unroll
  for (int o = 1; o < 64; o <<= 1) {
    const unsigned y = __shfl_up(x2, o);
    if ((tid & 63) >= o) x2 += y;
  }
  if ((tid & 63) == 63) wsum[tid >> 6] = x2;
  __syncthreads();
  unsigned off2 = 0;
  for (int w2 = 0; w2 < (tid >> 6); ++w2) off2 += wsum[w2];
  unsigned rk = (x2 - (unsigned)lc) + off2;    // exclusive rank in index order
  #pragma unroll
  for (int j = 0; j < 16; ++j) {
    if (keys[base + j] == prefix) {
      if (rk < remaining) trow[ngt + (int)rk] = base + j;
      ++rk;
    }
  }
}

// ---------------- V mean, stage 1 ----------------
__global__ __launch_bounds__(256) void k_vmean1(const float* __restrict__ v,
                                                float* __restrict__ vpart) {
  const int blk = blockIdx.x;
  const int b   = blk >> 6;
  const int c   = blk & 63;
  const int t   = threadIdx.x;
  const int hd4 = t & 127;
  const int p   = t >> 7;
  const float4* base = (const float4*)(v + ((size_t)b * L_ + (size_t)c * VCH) * (H_ * D_)) + hd4;
  float4 acc = {0.f, 0.f, 0.f, 0.f};
  for (int l = p; l < VCH; l += 2) {
    const float4 x = base[(size_t)l * 128];
    acc.x += x.x; acc.y += x.y; acc.z += x.z; acc.w += x.w;
  }
  __shared__ float4 s[2][128];
  s[p][hd4] = acc;
  __syncthreads();
  if (t < 128) {
    const float4 a = s[0][t], b2 = s[1][t];
    const float4 r = {a.x + b2.x, a.y + b2.y, a.z + b2.z, a.w + b2.w};
    ((float4*)vpart)[(size_t)blk * 128 + t] = r;
  }
}

// ---------------- V mean, stage 2 ----------------
__global__ __launch_bounds__(512) void k_vmean2(const float* __restrict__ vpart,
                                                float* __restrict__ vmean) {
  const int b = blockIdx.x, t = threadIdx.x;
  float acc = 0.f;
  for (int c = 0; c < 64; ++c)
    acc += vpart[((size_t)(b * 64 + c)) * 512 + t];
  vmean[b * 512 + t] = acc * (1.0f / L_);
}

// ---------------- scores = (Q_top @ K^T) * scale ----------------
__global__ __launch_bounds__(256) void k_scores(const float* __restrict__ q,
                                                const float* __restrict__ k,
                                                const int* __restrict__ top,
                                                float* __restrict__ scores) {
  __shared__ float k_lds[256 * 65];
  __shared__ __align__(16) float q_lds[NT * D_];
  const int bh = blockIdx.x >> 4, kb = blockIdx.x & 15;
  const int b = bh >> 3, h = bh & 7;

  const float* kbase = k + (((size_t)b * L_ + kb * 256) * H_ + h) * D_;
  for (int fi = threadIdx.x; fi < 4096; fi += 256) {
    const int j = fi >> 4, d4 = fi & 15;
    const float4 kv = *(const float4*)(kbase + (size_t)j * H_ * D_ + d4 * 4);
    float* dst = &k_lds[j * 65 + d4 * 4];
    dst[0] = kv.x; dst[1] = kv.y; dst[2] = kv.z; dst[3] = kv.w;
  }
  for (int fi = threadIdx.x; fi < NT * D_; fi += 256) {
    const int n = fi >> 6, d = fi & 63;
    const int qi = top[bh * NT + n];
    q_lds[fi] = q[(((size_t)b * L_ + qi) * H_ + h) * D_ + d];
  }
  __syncthreads();

  const int w = threadIdx.x >> 6, lane = threadIdx.x & 63;
  const int jl = w * 64 + lane;
  const int jj = kb * 256 + jl;
  const float* krow = &k_lds[jl * 65];
  for (int n = 0; n < NT; ++n) {
    float acc = 0.f;
    #pragma unroll
    for (int d4 = 0; d4 < 16; ++d4) {
      const float4 qq = *(const float4*)&q_lds[n * 64 + d4 * 4];
      acc += qq.x * krow[d4 * 4 + 0] + qq.y * krow[d4 * 4 + 1]
           + qq.z * krow[d4 * 4 + 2] + qq.w * krow[d4 * 4 + 3];
    }
    scores[((size_t)bh * NT + n) * L_ + jj] = acc * SCALE;
  }
}

// ---------------- row softmax over 4096, in place ----------------
__global__ __launch_bounds__(256) void k_softmax(float* __restrict__ scores) {
  __shared__ float buf[L_];
  __shared__ float red[4];
  const size_t base = (size_t)blockIdx.x * L_;
  float lm = -1e30f;
  for (int i = threadIdx.x; i < L_; i += 256) {
    const float v = scores[base + i];
    buf[i] = v;
    lm = fmaxf(lm, v);
  }
  #pragma unroll
  for (int o = 1; o < 64; o <<= 1) lm = fmaxf(lm, __shfl_xor(lm, o));
  if ((threadIdx.x & 63) == 0) red[threadIdx.x >> 6] = lm;
  __syncthreads();
  const float m = fmaxf(fmaxf(red[0], red[1]), fmaxf(red[2], red[3]));
  float ls = 0.f;
  for (int i = threadIdx.x; i < L_; i += 256) {
    const float p = __expf(buf[i] - m);
    buf[i] = p;
    ls += p;
  }
  #pragma unroll
  for (int o = 1; o < 64; o <<= 1) ls += __shfl_xor(ls, o);
  __syncthreads();
  if ((threadIdx.x & 63) == 0) red[threadIdx.x >> 6] = ls;
  __syncthreads();
  const float inv = 1.0f / (red[0] + red[1] + red[2] + red[3]);
  for (int i = threadIdx.x; i < L_; i += 256) scores[base + i] = buf[i] * inv;
}

// ---------------- attn @ V, key-chunk partials (LDS-staged p) ----------------
__global__ __launch_bounds__(256) void k_av(const float* __restrict__ p,
                                            const float* __restrict__ v,
                                            float* __restrict__ opart) {
  __shared__ __align__(16) float pl[256 * PLD];
  const int bh = blockIdx.x >> 4, jc = blockIdx.x & 15;
  const int b = bh >> 3, h = bh & 7;
  const int tid = threadIdx.x;

  const float* pbase = p + (size_t)bh * NT * L_ + jc * 256;
  for (int fi = tid; fi < NT * 256; fi += 256) {
    const int n = fi >> 8, j = fi & 255;
    pl[j * PLD + n] = pbase[(size_t)n * L_ + j];
  }
  __syncthreads();

  const int w = tid >> 6, d = tid & 63;
  float acc[NT];
  #pragma unroll
  for (int n = 0; n < NT; ++n) acc[n] = 0.f;

  const float* vbase = v + (((size_t)b * L_ + jc * 256 + w * 64) * H_ + h) * D_ + d;
  for (int jl = 0; jl < 64; ++jl) {
    const float vv = vbase[(size_t)jl * (H_ * D_)];
    const float* pr = &pl[(w * 64 + jl) * PLD];
    #pragma unroll
    for (int n4 = 0; n4 < 11; ++n4) {
      const float4 pv = *(const float4*)(pr + n4 * 4);
      acc[n4 * 4 + 0] += pv.x * vv;
      acc[n4 * 4 + 1] += pv.y * vv;
      acc[n4 * 4 + 2] += pv.z * vv;
      acc[n4 * 4 + 3] += pv.w * vv;
    }
    acc[44] += pr[44] * vv;
  }
  __syncthreads();

  float* scratch = pl;
  #pragma unroll
  for (int n = 0; n < NT; ++n) scratch[(w * NT + n) * 64 + d] = acc[n];
  __syncthreads();
  float* obase = opart + (((size_t)bh * NJC + jc) * NT) * 64;
  for (int i = tid; i < NT * 64; i += 256)
    obase[i] = scratch[i] + scratch[NT * 64 + i] + scratch[2 * NT * 64 + i] + scratch[3 * NT * 64 + i];
}

// ---------------- fill output with broadcast V-mean ----------------
__global__ __launch_bounds__(256) void k_fill(const float* __restrict__ vmean,
                                              float* __restrict__ out) {
  const size_t i = (size_t)blockIdx.x * 256 + threadIdx.x;
  const int d4 = (int)(i & 15);
  const int bh = (int)(i >> 16);
  const float4* vm = (const float4*)(vmean + bh * D_);
  ((float4*)out)[i] = vm[d4];
}

// ---------------- combine partials, scatter into out rows ----------------
__global__ void k_av2(const float* __restrict__ opart,
                      const int* __restrict__ top,
                      float* __restrict__ out) {
  const int bhn = blockIdx.x, bh = bhn / NT, n = bhn % NT;
  const int d = threadIdx.x;
  float acc = 0.f;
  #pragma unroll
  for (int jc = 0; jc < NJC; ++jc)
    acc += opart[(((size_t)bh * NJC + jc) * NT + n) * D_ + d];
  const int qi = top[bh * NT + n];
  out[((size_t)bh * L_ + qi) * D_ + d] = acc;
}

extern "C" void kernel_launch(void* const* d_in, const int* in_sizes, int n_in,
                              void* d_out, int out_size, void* d_ws, size_t ws_size,
                              hipStream_t stream) {
  const float* q    = (const float*)d_in[0];
  const float* k    = (const float*)d_in[1];
  const float* v    = (const float*)d_in[2];
  const int*   samp = (const int*)d_in[3];
  float* out = (float*)d_out;
  char*  ws  = (char*)d_ws;

  float* M     = (float*)ws;                 // 512 KB (dead after k_topk)
  int*   top   = (int*)(ws + 524288);
  float* vmean = (float*)(ws + 532480);
  float* opart = (float*)(ws + 540672);      // 5.9 MB
  float* vpart = M;                          // reuse M after k_topk
  float* scores = out;                       // d_out doubles as 23.6 MB scratch

  hipLaunchKernelGGL(k_m,       dim3(BH * L_ / 32), dim3(256), 0, stream, q, k, samp, M);  // 4096
  hipLaunchKernelGGL(k_topk,    dim3(BH),          dim3(256), 0, stream, M, top);
  hipLaunchKernelGGL(k_vmean1,  dim3(B_ * 64),     dim3(256), 0, stream, v, vpart);
  hipLaunchKernelGGL(k_vmean2,  dim3(B_),          dim3(512), 0, stream, vpart, vmean);
  hipLaunchKernelGGL(k_scores,  dim3(BH * 16),     dim3(256), 0, stream, q, k, top, scores);
  hipLaunchKernelGGL(k_softmax, dim3(BH * NT),     dim3(256), 0, stream, scores);
  hipLaunchKernelGGL(k_av,      dim3(BH * NJC),    dim3(256), 0, stream, scores, v, opart);
  hipLaunchKernelGGL(k_fill,    dim3(8192),        dim3(256), 0, stream, vmean, out);
  hipLaunchKernelGGL(k_av2,     dim3(BH * NT),     dim3(64),  0, stream, opart, top, out);
}